// Round 8
// baseline (298.711 us; speedup 1.0000x reference)
//
#include <hip/hip_runtime.h>
#include <math.h>

typedef __bf16 bf16_t;
typedef bf16_t bf16x8 __attribute__((ext_vector_type(8)));
typedef bf16_t bf16x4 __attribute__((ext_vector_type(4)));
typedef float f32x4 __attribute__((ext_vector_type(4)));

constexpr int S_ = 2048;
constexpr float SCALE = 0.125f;  // 1/sqrt(64)

#define MFMA_B16(a, b, c) __builtin_amdgcn_mfma_f32_16x16x32_bf16(a, b, c, 0, 0, 0)

// s_waitcnt immediates (gfx9 enc): [3:0]=vmcnt_lo, [6:4]=expcnt, [12:8]=lgkmcnt
#define WAIT_VM0() __builtin_amdgcn_s_waitcnt(0x0F70)
#define WAIT_VM1() __builtin_amdgcn_s_waitcnt(0x0F71)
#define WAIT_VM2() __builtin_amdgcn_s_waitcnt(0x0F72)
#define WAIT_VM4() __builtin_amdgcn_s_waitcnt(0x0F74)
#define BARRIER()  __builtin_amdgcn_s_barrier()

typedef __attribute__((address_space(1))) const void* as1_cvp;
typedef __attribute__((address_space(3))) void* as3_vp;

__device__ __forceinline__ void gl2lds16(const void* g, void* l)
{
    __builtin_amdgcn_global_load_lds((as1_cvp)g, (as3_vp)l, 16, 0, 0);
}

// ---------------------------------------------------------------------------
// LDS slot swizzle for row-major [*][32]bf16 tiles (64B rows, 4x16B slots):
//   slot' = slot ^ ((row>>1)&3)
// Linear LDS dest (global_load_lds requirement) + pre-swizzled global source
// column; fragment reads apply the same XOR. 2-way (free) bank aliasing.
// ---------------------------------------------------------------------------
#define SRC_SWZ8(lane) ((((lane) & 3) ^ (((lane) >> 3) & 3)) * 8)
#define RD_SWZ8(quad, l15) ((((quad) ^ (((l15) >> 1) & 3))) * 8)

// ---------------------------------------------------------------------------
// prep: cast x -> bf16 (blocks 0..1023), transpose-cast 4 weights (1024..2047),
// zero vsp (block 2048)
// ---------------------------------------------------------------------------
__global__ __launch_bounds__(256) void prep(const float* __restrict__ x,
                                            const float* __restrict__ Wq,
                                            const float* __restrict__ Wk,
                                            const float* __restrict__ Wv,
                                            const float* __restrict__ Wo,
                                            bf16_t* __restrict__ xb,
                                            bf16_t* __restrict__ Wqt,
                                            bf16_t* __restrict__ Wkt,
                                            bf16_t* __restrict__ Wvt,
                                            bf16_t* __restrict__ Wot,
                                            float* __restrict__ vsp)
{
    __shared__ float T[64][65];
    const int blk = blockIdx.x;
    const int tid = threadIdx.x;
    if (blk < 1024) {
#pragma unroll
        for (int u = 0; u < 4; ++u) {
            const int g = blk * 1024 + u * 256 + tid;
            const float4 v = ((const float4*)x)[g];
            bf16x4 o;
            o[0] = (bf16_t)v.x; o[1] = (bf16_t)v.y;
            o[2] = (bf16_t)v.z; o[3] = (bf16_t)v.w;
            *(bf16x4*)&xb[(size_t)g * 4] = o;
        }
    } else if (blk < 2048) {
        const int rem = blk - 1024;
        const int wsel = rem >> 8, t = rem & 255;
        const float* src = (wsel == 0) ? Wq : (wsel == 1) ? Wk : (wsel == 2) ? Wv : Wo;
        bf16_t* dst = (wsel == 0) ? Wqt : (wsel == 1) ? Wkt : (wsel == 2) ? Wvt : Wot;
        const int k0 = (t >> 4) * 64, n0 = (t & 15) * 64;
        const int rr = tid >> 4, c4 = (tid & 15) * 4;
#pragma unroll
        for (int u = 0; u < 4; ++u) {
            const float4 v = *(const float4*)&src[(size_t)(k0 + u * 16 + rr) * 1024 + n0 + c4];
            T[u * 16 + rr][c4 + 0] = v.x; T[u * 16 + rr][c4 + 1] = v.y;
            T[u * 16 + rr][c4 + 2] = v.z; T[u * 16 + rr][c4 + 3] = v.w;
        }
        __syncthreads();
#pragma unroll
        for (int u = 0; u < 4; ++u) {
            bf16x4 o;
#pragma unroll
            for (int e = 0; e < 4; ++e) o[e] = (bf16_t)T[c4 + e][u * 16 + rr];
            *(bf16x4*)&dst[(size_t)(n0 + u * 16 + rr) * 1024 + k0 + c4] = o;
        }
    } else {
#pragma unroll
        for (int u = 0; u < 8; ++u) vsp[u * 256 + tid] = 0.f;
    }
}

// ---------------------------------------------------------------------------
// bf16 MFMA GEMM, tri-buffered, fully unrolled K-loop (static buffer indices).
// 2 tiles in flight, vmcnt(4) retires only the older. LDS slot-swizzled.
// MODE 0: f32 store to dst[m][1024].
// MODE 1: bf16 store to [bh][s][64] (Q/K heads layout).
// MODE 2: bf16 store TRANSPOSED to VhT[bh][d][s] (A=Wvt, Bt=xb: m=hd, n=s)
//         + vsum (sum over s of V) from f32 acc.
// ---------------------------------------------------------------------------
template <int MODE>
__device__ __forceinline__ void mfma_gemm_body(bf16_t* __restrict__ As,
                                               bf16_t* __restrict__ Bs,
                                               const bf16_t* __restrict__ A,
                                               const bf16_t* __restrict__ Bt,
                                               void* __restrict__ dst,
                                               float* __restrict__ vsum_out,
                                               int m0, int n0)
{
    const int tid = threadIdx.x;
    const int lane = tid & 63, wid = tid >> 6;
    const int l15 = lane & 15, quad = lane >> 4;
    const int wm = (wid & 1) * 64, wn = (wid >> 1) * 64;

    const int srow = wid * 32 + (lane >> 2);
    const int scg8 = SRC_SWZ8(lane);   // pre-swizzled source slot
    const bf16_t* Ag0 = A  + (size_t)(m0 + srow) * 1024 + scg8;
    const bf16_t* Ag1 = A  + (size_t)(m0 + srow + 16) * 1024 + scg8;
    const bf16_t* Bg0 = Bt + (size_t)(n0 + srow) * 1024 + scg8;
    const bf16_t* Bg1 = Bt + (size_t)(n0 + srow + 16) * 1024 + scg8;

    const int rs = RD_SWZ8(quad, l15); // swizzled read slot

    f32x4 acc[4][4];
#pragma unroll
    for (int i = 0; i < 4; ++i)
#pragma unroll
        for (int j = 0; j < 4; ++j) acc[i][j] = (f32x4){0.f, 0.f, 0.f, 0.f};

    // prologue: tiles 0,1 into buffers 0,1
#pragma unroll
    for (int p = 0; p < 2; ++p) {
        const int k0 = p * 32;
        gl2lds16(Ag0 + k0, As + p * 4096 + (wid * 2 + 0) * 512);
        gl2lds16(Ag1 + k0, As + p * 4096 + (wid * 2 + 1) * 512);
        gl2lds16(Bg0 + k0, Bs + p * 4096 + (wid * 2 + 0) * 512);
        gl2lds16(Bg1 + k0, Bs + p * 4096 + (wid * 2 + 1) * 512);
    }

#pragma unroll
    for (int it = 0; it < 32; ++it) {
        if (it < 30) WAIT_VM4(); else WAIT_VM0();
        BARRIER();
        if (it < 30) {
            const int k0 = (it + 2) * 32;
            const int sb = (it + 2) % 3;          // compile-time after unroll
            gl2lds16(Ag0 + k0, As + sb * 4096 + (wid * 2 + 0) * 512);
            gl2lds16(Ag1 + k0, As + sb * 4096 + (wid * 2 + 1) * 512);
            gl2lds16(Bg0 + k0, Bs + sb * 4096 + (wid * 2 + 0) * 512);
            gl2lds16(Bg1 + k0, Bs + sb * 4096 + (wid * 2 + 1) * 512);
        }
        const int cb = it % 3;                    // compile-time after unroll
        bf16x8 af[4], bfr[4];
#pragma unroll
        for (int mt = 0; mt < 4; ++mt)
            af[mt] = *(const bf16x8*)&As[cb * 4096 + (wm + mt * 16 + l15) * 32 + rs];
#pragma unroll
        for (int nt = 0; nt < 4; ++nt)
            bfr[nt] = *(const bf16x8*)&Bs[cb * 4096 + (wn + nt * 16 + l15) * 32 + rs];
#pragma unroll
        for (int mt = 0; mt < 4; ++mt)
#pragma unroll
            for (int nt = 0; nt < 4; ++nt)
                acc[mt][nt] = MFMA_B16(bfr[nt], af[mt], acc[mt][nt]);  // lane=m, regs=n
    }

#pragma unroll
    for (int mt = 0; mt < 4; ++mt) {
        const int m = m0 + wm + mt * 16 + l15;
#pragma unroll
        for (int nt = 0; nt < 4; ++nt) {
            const int nb = n0 + wn + nt * 16 + quad * 4;
            if (MODE == 0) {
                *(f32x4*)&((float*)dst)[(size_t)m * 1024 + nb] = acc[mt][nt];
            } else if (MODE == 1) {
                const int bb = m >> 11, s = m & 2047;
                const int hh = nb >> 6, d = nb & 63;
                bf16x4 o;
#pragma unroll
                for (int u = 0; u < 4; ++u) o[u] = (bf16_t)acc[mt][nt][u];
                *(bf16x4*)&((bf16_t*)dst)[((size_t)(bb * 16 + hh) * 2048 + s) * 64 + d] = o;
            } else {
                // MODE 2: m = hd, n = s; store V^T[bh][d][s] contiguous in s
                const int bb = n0 >> 11;          // n-tile (128) within one bb
                const int hh = m >> 6, dd = m & 63;
                bf16x4 o;
#pragma unroll
                for (int u = 0; u < 4; ++u) o[u] = (bf16_t)acc[mt][nt][u];
                *(bf16x4*)&((bf16_t*)dst)[((size_t)(bb * 16 + hh) * 64 + dd) * 2048 + (nb & 2047)] = o;
            }
        }
    }

    if (MODE == 2 && vsum_out != nullptr) {
        const int bb = n0 >> 11;
#pragma unroll
        for (int mt = 0; mt < 4; ++mt) {
            float p = 0.f;
#pragma unroll
            for (int nt = 0; nt < 4; ++nt)
                p += acc[mt][nt][0] + acc[mt][nt][1] + acc[mt][nt][2] + acc[mt][nt][3];
            p += __shfl_xor(p, 16);   // reduce over quad (s sub-range)
            p += __shfl_xor(p, 32);
            if (quad == 0) {
                const int m = m0 + wm + mt * 16 + l15;   // hd
                atomicAdd(&vsum_out[(bb * 16 + (m >> 6)) * 64 + (m & 63)], p);
            }
        }
    }
}

// L2-aware remap: HW XCD = dispatch_linear % 8 = blockIdx.x. Each XCD owns a
// contiguous panel strip so A+B working set fits the 4 MB per-XCD L2.
__device__ __forceinline__ int remap_m(void) { return (blockIdx.x << 2) + (blockIdx.y >> 3); }
__device__ __forceinline__ int remap_n(void) { return blockIdx.y & 7; }

__global__ __launch_bounds__(256) void gemm_qkv_mfma(const bf16_t* __restrict__ xb,
                                                     const bf16_t* __restrict__ Wqt,
                                                     const bf16_t* __restrict__ Wkt,
                                                     const bf16_t* __restrict__ Wvt,
                                                     bf16_t* Qh, bf16_t* Kh, bf16_t* VhT,
                                                     float* vsp)
{
    __shared__ bf16_t As[12288];  // 3 x [128][32], slot-swizzled (shared by both paths)
    __shared__ bf16_t Bs[12288];
    if (blockIdx.z == 2) {
        // V^T GEMM: m-dim = hd (8 tiles), n-dim = s (32 tiles); swap remaps so
        // XCD x gets an s-strip (1MB xb) + full Wvt (2MB) -> L2-resident.
        mfma_gemm_body<2>(As, Bs, Wvt, xb, VhT, vsp, remap_n() * 128, remap_m() * 128);
    } else {
        const bf16_t* Bt = (blockIdx.z == 0) ? Wqt : Wkt;
        bf16_t* dst = (blockIdx.z == 0) ? Qh : Kh;
        mfma_gemm_body<1>(As, Bs, xb, Bt, dst, nullptr, remap_m() * 128, remap_n() * 128);
    }
}

__global__ __launch_bounds__(256) void gemm_out_mfma(const bf16_t* __restrict__ attn,
                                                     const bf16_t* __restrict__ Wot,
                                                     float* __restrict__ out)
{
    __shared__ bf16_t As[12288];
    __shared__ bf16_t Bs[12288];
    mfma_gemm_body<0>(As, Bs, attn, Wot, out, nullptr, remap_m() * 128, remap_n() * 128);
}

// ---------------------------------------------------------------------------
// Fused attention kernel, R8: 512 blocks x 512 THREADS (8 waves). Same 128
// q-rows per block; per-wave work halved; 2 blocks/CU co-resident -> 16
// waves/CU = 4 waves/SIMD (2x R7) for latency hiding — R7 showed ~48% of
// cycles were stall at 2 waves/SIMD with identical kernels at 48.0 us.
// Phase A: 32 chunks of 64 j, 4 buffers, depth-3 counted vmcnt (1 gl2lds per
// thread per chunk -> VM2 steady / VM1 / VM0 tail). Wave w: i-tiles
// (w&1)*4..+4, j-tile w>>1 (8 MFMA/chunk).
// Phase B: 6 chunks of 64 j; wave w owns i-tile w. Ws is wave-private ->
// QK->PV mid-barrier removed. V staged from pre-transposed VhT (swizzled).
// Repartition only — every output element sees the identical op sequence.
// LDS 52224 B. __launch_bounds__(512,4) caps VGPR at 128 (2 blocks/CU).
// ---------------------------------------------------------------------------
__global__ __launch_bounds__(512, 4) void attn_k(const bf16_t* __restrict__ Qh,
                                                 const bf16_t* __restrict__ Kh,
                                                 const bf16_t* __restrict__ VhT,
                                                 const float* __restrict__ vsp,
                                                 bf16_t* __restrict__ attn)
{
    __shared__ bf16_t Qs[8192];           // [2 half][128][32], lives A+B
    __shared__ float mr_sh[128];          // row max * SCALE, A -> B
    __shared__ __align__(16) char uni[35328];  // phase-exclusive union

    // phase A views
    bf16_t* KsB = (bf16_t*)uni;                       // 4 x [2][64][32] = 32768 B
    float*  msh = (float*)(uni + 32768);              // [8 wave][4 it][16] = 2048 B
    // phase B views
    bf16_t* Ks2 = (bf16_t*)uni;                       // [2][64][32]     = 8192 B
    bf16_t* VtL = (bf16_t*)(uni + 8192);              // [64 d][64 j] swz = 8192 B
    bf16_t* Ws  = (bf16_t*)(uni + 16384);             // [128][72]       = 18432 B
    float*  zsh = (float*)(uni + 34816);              // [8][16]         = 512 B

    const int tid = threadIdx.x;
    const int lane = tid & 63, wid = tid >> 6;        // 8 waves
    const int l15 = lane & 15, quad = lane >> 4;

    const int f = blockIdx.x;
    const int seq = f >> 3;
    const int bh = (f & 7) + 8 * (seq >> 4);   // XCD-locality
    const int i0 = (seq & 15) * 128;
    const int b = bh >> 4, h = bh & 15;
    const bf16_t* Qb  = Qh  + (size_t)bh * 131072;
    const bf16_t* Kb  = Kh  + (size_t)bh * 131072;
    const bf16_t* VbT = VhT + (size_t)bh * 131072;

    const int ssw = SRC_SWZ8(lane);
    const int rs  = RD_SWZ8(quad, l15);

    // ======================= phase A: full-row max =========================
    // stage Q [2][128][32] (16 granules, 2/wave)
#pragma unroll
    for (int c = 0; c < 2; ++c) {
        const int gg = wid * 2 + c;
        const int half = gg >> 3;
        const int row = (gg & 7) * 16 + (lane >> 2);
        gl2lds16(Qb + (size_t)(i0 + row) * 64 + half * 32 + ssw, Qs + gg * 512);
    }
    // prologue: K chunks 0,1,2 into buffers 0,1,2 (1 gl2lds/thread/chunk)
#pragma unroll
    for (int p = 0; p < 3; ++p) {
        const int gg = wid;                           // 0..7
        const int half = gg >> 2;
        const int row = (gg & 3) * 16 + (lane >> 2);
        gl2lds16(Kb + (size_t)(p * 64 + row) * 64 + half * 32 + ssw,
                 KsB + p * 4096 + gg * 512);
    }
    __syncthreads();   // full drain: Q + chunks 0-2 resident

    // wave's 4 i-tiles: it = (wid&1)*4 + mt'
    const int itb = (wid & 1) * 4;
    const int jt  = wid >> 1;        // wave's j-tile within each 64-j chunk
    bf16x8 af[4][2];
#pragma unroll
    for (int mt = 0; mt < 4; ++mt)
#pragma unroll
        for (int ks = 0; ks < 2; ++ks)
            af[mt][ks] = *(const bf16x8*)&Qs[ks * 4096 + ((itb + mt) * 16 + l15) * 32 + rs];

    float vm[4];
#pragma unroll
    for (int mt = 0; mt < 4; ++mt) vm[mt] = -3.0e38f;

    for (int jc = 0; jc < 32; ++jc) {
        if (jc < 30) WAIT_VM2();        // own chunk-jc load landed (3 chunks deep)
        else if (jc == 30) WAIT_VM1();
        else WAIT_VM0();
        BARRIER();                      // all waves: jc landed; jc-1 compute done
        if (jc < 29) {
            const int sb = (jc + 3) & 3;
            const int gg = wid;
            const int half = gg >> 2;
            const int row = (gg & 3) * 16 + (lane >> 2);
            gl2lds16(Kb + (size_t)((jc + 3) * 64 + row) * 64 + half * 32 + ssw,
                     KsB + sb * 4096 + gg * 512);
        }
        const int cb = jc & 3;
        const bf16x8 b0 = *(const bf16x8*)&KsB[cb * 4096 + (jt * 16 + l15) * 32 + rs];
        const bf16x8 b1 = *(const bf16x8*)&KsB[cb * 4096 + 2048 + (jt * 16 + l15) * 32 + rs];
#pragma unroll
        for (int mt = 0; mt < 4; ++mt) {
            f32x4 t = (f32x4){0.f, 0.f, 0.f, 0.f};
            t = MFMA_B16(b0, af[mt][0], t);   // lane = i, regs = j
            t = MFMA_B16(b1, af[mt][1], t);
            const float u = fmaxf(fmaxf(t[0], t[1]), t[2]);      // v_max3
            vm[mt] = fmaxf(fmaxf(u, t[3]), vm[mt]);              // v_max3
        }
    }

    // per-wave partial -> msh
#pragma unroll
    for (int mt = 0; mt < 4; ++mt) {
        float v = vm[mt];
        v = fmaxf(v, __shfl_xor(v, 16));
        v = fmaxf(v, __shfl_xor(v, 32));
        if (quad == 0) msh[wid * 64 + mt * 16 + l15] = v;
    }
    __syncthreads();

    // cross-wave combine -> mr_sh: row i = mt*16+il covered by waves
    // w = 2*jtx + (mt>>2), jtx in [0,4), local i-tile idx mt&3.
    if (tid < 128) {
        const int mt = tid >> 4, il = tid & 15;
        const int p = mt >> 2, lt = mt & 3;
        const float v = fmaxf(fmaxf(msh[(0 + p) * 64 + lt * 16 + il],
                                    msh[(2 + p) * 64 + lt * 16 + il]),
                              fmaxf(msh[(4 + p) * 64 + lt * 16 + il],
                                    msh[(6 + p) * 64 + lt * 16 + il]));
        mr_sh[tid] = v * SCALE;
    }
    __syncthreads();   // mr_sh visible; ALL phase-A union reads complete

    // ======================= phase B: banded attention =====================
    // wave owns i-tile mt = wid
    bf16x8 aq[2];
#pragma unroll
    for (int ks = 0; ks < 2; ++ks)
        aq[ks] = *(const bf16x8*)&Qs[ks * 4096 + (wid * 16 + l15) * 32 + rs];

    float mreg[4];
#pragma unroll
    for (int r = 0; r < 4; ++r)
        mreg[r] = mr_sh[wid * 16 + quad * 4 + r];

    f32x4 vsd4[4];
#pragma unroll
    for (int dt = 0; dt < 4; ++dt)
        vsd4[dt] = *(const f32x4*)&vsp[bh * 64 + dt * 16 + quad * 4];

    f32x4 accO[4];
#pragma unroll
    for (int dt = 0; dt < 4; ++dt) accO[dt] = (f32x4){0.f, 0.f, 0.f, 0.f};
    float zp[4] = {0.f, 0.f, 0.f, 0.f};

    for (int cb2 = 0; cb2 < 6; ++cb2) {
        const int jb = i0 - 128 + cb2 * 64;
        if (jb < 0 || jb >= S_) continue;  // block-uniform

        __syncthreads();                   // prior chunk's Ks2/VtL readers done
        // K chunk (slot-swizzled): 8 granules, 1/wave
        {
            const int gg = wid;
            const int half = gg >> 2;
            const int row = (gg & 3) * 16 + (lane >> 2);
            gl2lds16(Kb + (size_t)(jb + row) * 64 + half * 32 + ssw, Ks2 + gg * 512);
        }
        // V chunk from VhT: [64 d][64 j], phys slot p holds logical p^(d&7).
        {
            const int gg = wid;
            const int d = gg * 8 + (lane >> 3);
            const int jl = (lane & 7) ^ ((lane >> 3) & 7);
            gl2lds16(VbT + (size_t)d * 2048 + jb + jl * 8, VtL + gg * 512);
        }
        __syncthreads();

        // QK^T + exp weights (wave's own 16 i-rows)
#pragma unroll
        for (int jt4 = 0; jt4 < 4; ++jt4) {
            const bf16x8 k0 = *(const bf16x8*)&Ks2[(jt4 * 16 + l15) * 32 + rs];
            const bf16x8 k1 = *(const bf16x8*)&Ks2[2048 + (jt4 * 16 + l15) * 32 + rs];
            f32x4 sc = (f32x4){0.f, 0.f, 0.f, 0.f};
            sc = MFMA_B16(aq[0], k0, sc);   // lane = j, regs = i
            sc = MFMA_B16(aq[1], k1, sc);
#pragma unroll
            for (int r = 0; r < 4; ++r) {
                const int ig = i0 + wid * 16 + quad * 4 + r;
                const int jg = jb + jt4 * 16 + l15;
                const int dd = jg - ig;
                const bool ok = (dd >= -128) && (dd <= 127);
                const float e1 = __expf(sc[r] * SCALE - mreg[r]);
                const float wv = ok ? (__expf(e1) - 1.0f) : 0.0f;
                const bf16_t wb = (bf16_t)wv;
                zp[r] += (float)wb;
                Ws[(wid * 16 + quad * 4 + r) * 72 + jt4 * 16 + l15] = wb;
            }
        }
        // NO barrier: Ws rows [wid*16, wid*16+16) are wave-private (write and
        // read below); VtL was drained by the post-staging __syncthreads.

        // PV
#pragma unroll
        for (int ks = 0; ks < 2; ++ks) {
            bf16x8 bv[4];
#pragma unroll
            for (int dt = 0; dt < 4; ++dt)
                bv[dt] = *(const bf16x8*)&VtL[(dt * 16 + l15) * 64 +
                                              (((ks * 4 + quad) ^ (l15 & 7)) * 8)];
            const bf16x8 aw = *(const bf16x8*)&Ws[(wid * 16 + l15) * 72 + ks * 32 + quad * 8];
#pragma unroll
            for (int dt = 0; dt < 4; ++dt)
                accO[dt] = MFMA_B16(bv[dt], aw, accO[dt]);  // lane=i, regs=d
        }
    }

#pragma unroll
    for (int r = 0; r < 4; ++r) {
        float z = zp[r];
        z += __shfl_xor(z, 1);
        z += __shfl_xor(z, 2);
        z += __shfl_xor(z, 4);
        z += __shfl_xor(z, 8);
        if (l15 == 0) zsh[wid * 16 + quad * 4 + r] = z + (float)S_;
    }
    __syncthreads();

    {
        const float rz = 1.0f / zsh[wid * 16 + l15];
        const int irow = i0 + wid * 16 + l15;
#pragma unroll
        for (int dt = 0; dt < 4; ++dt) {
            bf16x4 o;
#pragma unroll
            for (int r = 0; r < 4; ++r)
                o[r] = (bf16_t)((accO[dt][r] + vsd4[dt][r]) * rz);
            *(bf16x4*)&attn[(size_t)(b * S_ + irow) * 1024 + h * 64 + dt * 16 + quad * 4] = o;
        }
    }
}

// ---------------------------------------------------------------------------
// Launch: 4 kernels
// ---------------------------------------------------------------------------
extern "C" void kernel_launch(void* const* d_in, const int* in_sizes, int n_in,
                              void* d_out, int out_size, void* d_ws, size_t ws_size,
                              hipStream_t stream)
{
    const float* x  = (const float*)d_in[0];
    const float* Wq = (const float*)d_in[1];
    const float* Wk = (const float*)d_in[2];
    const float* Wv = (const float*)d_in[3];
    const float* Wo = (const float*)d_in[4];
    float* out = (float*)d_out;

    char* ws = (char*)d_ws;
    bf16_t* xb   = (bf16_t*)(ws + 0);
    bf16_t* Wqt  = (bf16_t*)(ws + 8388608);
    bf16_t* Wkt  = (bf16_t*)(ws + 10485760);
    bf16_t* Wvt  = (bf16_t*)(ws + 12582912);
    bf16_t* Wot  = (bf16_t*)(ws + 14680064);
    bf16_t* Qh   = (bf16_t*)(ws + 16777216);   // [bh][s][64]
    bf16_t* Kh   = (bf16_t*)(ws + 25165824);   // [bh][s][64]
    bf16_t* VhT  = (bf16_t*)(ws + 33554432);   // [bh][d][s]  (V transposed)
    bf16_t* attn = (bf16_t*)(ws + 41943040);   // [m][1024]
    float*  vsp  = (float*)(ws + 50331648);    // [bh][64] f32, zeroed by prep

    prep<<<2049, 256, 0, stream>>>(x, Wq, Wk, Wv, Wo, xb, Wqt, Wkt, Wvt, Wot, vsp);
    gemm_qkv_mfma<<<dim3(8, 32, 3), 256, 0, stream>>>(xb, Wqt, Wkt, Wvt, Qh, Kh, VhT, vsp);
    attn_k<<<512, 512, 0, stream>>>(Qh, Kh, VhT, vsp, attn);
    gemm_out_mfma<<<dim3(8, 32), 256, 0, stream>>>(attn, Wot, out);
}

// Round 9
// 227.180 us; speedup vs baseline: 1.3149x; 1.3149x over previous
//
#include <hip/hip_runtime.h>
#include <math.h>

typedef __bf16 bf16_t;
typedef bf16_t bf16x8 __attribute__((ext_vector_type(8)));
typedef bf16_t bf16x4 __attribute__((ext_vector_type(4)));
typedef float f32x4 __attribute__((ext_vector_type(4)));

constexpr int S_ = 2048;
constexpr float SCALE = 0.125f;  // 1/sqrt(64)

#define MFMA_B16(a, b, c) __builtin_amdgcn_mfma_f32_16x16x32_bf16(a, b, c, 0, 0, 0)

// s_waitcnt immediates (gfx9 enc): [3:0]=vmcnt_lo, [6:4]=expcnt, [12:8]=lgkmcnt
#define WAIT_VM0() __builtin_amdgcn_s_waitcnt(0x0F70)
#define WAIT_VM1() __builtin_amdgcn_s_waitcnt(0x0F71)
#define WAIT_VM2() __builtin_amdgcn_s_waitcnt(0x0F72)
#define WAIT_VM4() __builtin_amdgcn_s_waitcnt(0x0F74)
#define BARRIER()  __builtin_amdgcn_s_barrier()

typedef __attribute__((address_space(1))) const void* as1_cvp;
typedef __attribute__((address_space(3))) void* as3_vp;

__device__ __forceinline__ void gl2lds16(const void* g, void* l)
{
    __builtin_amdgcn_global_load_lds((as1_cvp)g, (as3_vp)l, 16, 0, 0);
}

// ---------------------------------------------------------------------------
// LDS slot swizzle for row-major [*][32]bf16 tiles (64B rows, 4x16B slots):
//   slot' = slot ^ ((row>>1)&3)
// Linear LDS dest (global_load_lds requirement) + pre-swizzled global source
// column; fragment reads apply the same XOR. 2-way (free) bank aliasing.
// ---------------------------------------------------------------------------
#define SRC_SWZ8(lane) ((((lane) & 3) ^ (((lane) >> 3) & 3)) * 8)
#define RD_SWZ8(quad, l15) ((((quad) ^ (((l15) >> 1) & 3))) * 8)

// ---------------------------------------------------------------------------
// prep: cast x -> bf16 (blocks 0..1023), transpose-cast 4 weights (1024..2047),
// zero vsp (block 2048)
// ---------------------------------------------------------------------------
__global__ __launch_bounds__(256) void prep(const float* __restrict__ x,
                                            const float* __restrict__ Wq,
                                            const float* __restrict__ Wk,
                                            const float* __restrict__ Wv,
                                            const float* __restrict__ Wo,
                                            bf16_t* __restrict__ xb,
                                            bf16_t* __restrict__ Wqt,
                                            bf16_t* __restrict__ Wkt,
                                            bf16_t* __restrict__ Wvt,
                                            bf16_t* __restrict__ Wot,
                                            float* __restrict__ vsp)
{
    __shared__ float T[64][65];
    const int blk = blockIdx.x;
    const int tid = threadIdx.x;
    if (blk < 1024) {
#pragma unroll
        for (int u = 0; u < 4; ++u) {
            const int g = blk * 1024 + u * 256 + tid;
            const float4 v = ((const float4*)x)[g];
            bf16x4 o;
            o[0] = (bf16_t)v.x; o[1] = (bf16_t)v.y;
            o[2] = (bf16_t)v.z; o[3] = (bf16_t)v.w;
            *(bf16x4*)&xb[(size_t)g * 4] = o;
        }
    } else if (blk < 2048) {
        const int rem = blk - 1024;
        const int wsel = rem >> 8, t = rem & 255;
        const float* src = (wsel == 0) ? Wq : (wsel == 1) ? Wk : (wsel == 2) ? Wv : Wo;
        bf16_t* dst = (wsel == 0) ? Wqt : (wsel == 1) ? Wkt : (wsel == 2) ? Wvt : Wot;
        const int k0 = (t >> 4) * 64, n0 = (t & 15) * 64;
        const int rr = tid >> 4, c4 = (tid & 15) * 4;
#pragma unroll
        for (int u = 0; u < 4; ++u) {
            const float4 v = *(const float4*)&src[(size_t)(k0 + u * 16 + rr) * 1024 + n0 + c4];
            T[u * 16 + rr][c4 + 0] = v.x; T[u * 16 + rr][c4 + 1] = v.y;
            T[u * 16 + rr][c4 + 2] = v.z; T[u * 16 + rr][c4 + 3] = v.w;
        }
        __syncthreads();
#pragma unroll
        for (int u = 0; u < 4; ++u) {
            bf16x4 o;
#pragma unroll
            for (int e = 0; e < 4; ++e) o[e] = (bf16_t)T[c4 + e][u * 16 + rr];
            *(bf16x4*)&dst[(size_t)(n0 + u * 16 + rr) * 1024 + k0 + c4] = o;
        }
    } else {
#pragma unroll
        for (int u = 0; u < 8; ++u) vsp[u * 256 + tid] = 0.f;
    }
}

// ---------------------------------------------------------------------------
// bf16 MFMA GEMM, tri-buffered, fully unrolled K-loop (static buffer indices).
// 2 tiles in flight, vmcnt(4) retires only the older. LDS slot-swizzled.
// MODE 0: f32 store to dst[m][1024].
// MODE 1: bf16 store to [bh][s][64] (Q/K heads layout).
// MODE 2: bf16 store TRANSPOSED to VhT[bh][d][s] (A=Wvt, Bt=xb: m=hd, n=s)
//         + vsum (sum over s of V) from f32 acc.
// ---------------------------------------------------------------------------
template <int MODE>
__device__ __forceinline__ void mfma_gemm_body(bf16_t* __restrict__ As,
                                               bf16_t* __restrict__ Bs,
                                               const bf16_t* __restrict__ A,
                                               const bf16_t* __restrict__ Bt,
                                               void* __restrict__ dst,
                                               float* __restrict__ vsum_out,
                                               int m0, int n0)
{
    const int tid = threadIdx.x;
    const int lane = tid & 63, wid = tid >> 6;
    const int l15 = lane & 15, quad = lane >> 4;
    const int wm = (wid & 1) * 64, wn = (wid >> 1) * 64;

    const int srow = wid * 32 + (lane >> 2);
    const int scg8 = SRC_SWZ8(lane);   // pre-swizzled source slot
    const bf16_t* Ag0 = A  + (size_t)(m0 + srow) * 1024 + scg8;
    const bf16_t* Ag1 = A  + (size_t)(m0 + srow + 16) * 1024 + scg8;
    const bf16_t* Bg0 = Bt + (size_t)(n0 + srow) * 1024 + scg8;
    const bf16_t* Bg1 = Bt + (size_t)(n0 + srow + 16) * 1024 + scg8;

    const int rs = RD_SWZ8(quad, l15); // swizzled read slot

    f32x4 acc[4][4];
#pragma unroll
    for (int i = 0; i < 4; ++i)
#pragma unroll
        for (int j = 0; j < 4; ++j) acc[i][j] = (f32x4){0.f, 0.f, 0.f, 0.f};

    // prologue: tiles 0,1 into buffers 0,1
#pragma unroll
    for (int p = 0; p < 2; ++p) {
        const int k0 = p * 32;
        gl2lds16(Ag0 + k0, As + p * 4096 + (wid * 2 + 0) * 512);
        gl2lds16(Ag1 + k0, As + p * 4096 + (wid * 2 + 1) * 512);
        gl2lds16(Bg0 + k0, Bs + p * 4096 + (wid * 2 + 0) * 512);
        gl2lds16(Bg1 + k0, Bs + p * 4096 + (wid * 2 + 1) * 512);
    }

#pragma unroll
    for (int it = 0; it < 32; ++it) {
        if (it < 30) WAIT_VM4(); else WAIT_VM0();
        BARRIER();
        if (it < 30) {
            const int k0 = (it + 2) * 32;
            const int sb = (it + 2) % 3;          // compile-time after unroll
            gl2lds16(Ag0 + k0, As + sb * 4096 + (wid * 2 + 0) * 512);
            gl2lds16(Ag1 + k0, As + sb * 4096 + (wid * 2 + 1) * 512);
            gl2lds16(Bg0 + k0, Bs + sb * 4096 + (wid * 2 + 0) * 512);
            gl2lds16(Bg1 + k0, Bs + sb * 4096 + (wid * 2 + 1) * 512);
        }
        const int cb = it % 3;                    // compile-time after unroll
        bf16x8 af[4], bfr[4];
#pragma unroll
        for (int mt = 0; mt < 4; ++mt)
            af[mt] = *(const bf16x8*)&As[cb * 4096 + (wm + mt * 16 + l15) * 32 + rs];
#pragma unroll
        for (int nt = 0; nt < 4; ++nt)
            bfr[nt] = *(const bf16x8*)&Bs[cb * 4096 + (wn + nt * 16 + l15) * 32 + rs];
#pragma unroll
        for (int mt = 0; mt < 4; ++mt)
#pragma unroll
            for (int nt = 0; nt < 4; ++nt)
                acc[mt][nt] = MFMA_B16(bfr[nt], af[mt], acc[mt][nt]);  // lane=m, regs=n
    }

#pragma unroll
    for (int mt = 0; mt < 4; ++mt) {
        const int m = m0 + wm + mt * 16 + l15;
#pragma unroll
        for (int nt = 0; nt < 4; ++nt) {
            const int nb = n0 + wn + nt * 16 + quad * 4;
            if (MODE == 0) {
                *(f32x4*)&((float*)dst)[(size_t)m * 1024 + nb] = acc[mt][nt];
            } else if (MODE == 1) {
                const int bb = m >> 11, s = m & 2047;
                const int hh = nb >> 6, d = nb & 63;
                bf16x4 o;
#pragma unroll
                for (int u = 0; u < 4; ++u) o[u] = (bf16_t)acc[mt][nt][u];
                *(bf16x4*)&((bf16_t*)dst)[((size_t)(bb * 16 + hh) * 2048 + s) * 64 + d] = o;
            } else {
                // MODE 2: m = hd, n = s; store V^T[bh][d][s] contiguous in s
                const int bb = n0 >> 11;          // n-tile (128) within one bb
                const int hh = m >> 6, dd = m & 63;
                bf16x4 o;
#pragma unroll
                for (int u = 0; u < 4; ++u) o[u] = (bf16_t)acc[mt][nt][u];
                *(bf16x4*)&((bf16_t*)dst)[((size_t)(bb * 16 + hh) * 64 + dd) * 2048 + (nb & 2047)] = o;
            }
        }
    }

    if (MODE == 2 && vsum_out != nullptr) {
        const int bb = n0 >> 11;
#pragma unroll
        for (int mt = 0; mt < 4; ++mt) {
            float p = 0.f;
#pragma unroll
            for (int nt = 0; nt < 4; ++nt)
                p += acc[mt][nt][0] + acc[mt][nt][1] + acc[mt][nt][2] + acc[mt][nt][3];
            p += __shfl_xor(p, 16);   // reduce over quad (s sub-range)
            p += __shfl_xor(p, 32);
            if (quad == 0) {
                const int m = m0 + wm + mt * 16 + l15;   // hd
                atomicAdd(&vsum_out[(bb * 16 + (m >> 6)) * 64 + (m & 63)], p);
            }
        }
    }
}

// L2-aware remap: HW XCD = dispatch_linear % 8 = blockIdx.x. Each XCD owns a
// contiguous panel strip so A+B working set fits the 4 MB per-XCD L2.
__device__ __forceinline__ int remap_m(void) { return (blockIdx.x << 2) + (blockIdx.y >> 3); }
__device__ __forceinline__ int remap_n(void) { return blockIdx.y & 7; }

__global__ __launch_bounds__(256) void gemm_qkv_mfma(const bf16_t* __restrict__ xb,
                                                     const bf16_t* __restrict__ Wqt,
                                                     const bf16_t* __restrict__ Wkt,
                                                     const bf16_t* __restrict__ Wvt,
                                                     bf16_t* Qh, bf16_t* Kh, bf16_t* VhT,
                                                     float* vsp)
{
    __shared__ bf16_t As[12288];  // 3 x [128][32], slot-swizzled (shared by both paths)
    __shared__ bf16_t Bs[12288];
    if (blockIdx.z == 2) {
        // V^T GEMM: m-dim = hd (8 tiles), n-dim = s (32 tiles); swap remaps so
        // XCD x gets an s-strip (1MB xb) + full Wvt (2MB) -> L2-resident.
        mfma_gemm_body<2>(As, Bs, Wvt, xb, VhT, vsp, remap_n() * 128, remap_m() * 128);
    } else {
        const bf16_t* Bt = (blockIdx.z == 0) ? Wqt : Wkt;
        bf16_t* dst = (blockIdx.z == 0) ? Qh : Kh;
        mfma_gemm_body<1>(As, Bs, xb, Bt, dst, nullptr, remap_m() * 128, remap_n() * 128);
    }
}

__global__ __launch_bounds__(256) void gemm_out_mfma(const bf16_t* __restrict__ attn,
                                                     const bf16_t* __restrict__ Wot,
                                                     float* __restrict__ out)
{
    __shared__ bf16_t As[12288];
    __shared__ bf16_t Bs[12288];
    mfma_gemm_body<0>(As, Bs, attn, Wot, out, nullptr, remap_m() * 128, remap_n() * 128);
}

// ---------------------------------------------------------------------------
// Fused attention kernel, R9: 512 blocks x 512 threads (8 waves). Identical
// to R8 EXCEPT __launch_bounds__(512, 2): R8's (512,4) forced the allocator
// to 64 VGPR -> catastrophic scratch spill (FETCH 168 MB / WRITE 309 MB per
// dispatch, MfmaUtil 5%, 170+ us). (512,2) caps at 256; natural allocation
// ~100 VGPR <= 128 still allows 2 blocks/CU (16 waves, 4/SIMD) at runtime —
// occupancy follows ACTUAL VGPR/LDS, not the declared bound.
// ---------------------------------------------------------------------------
__global__ __launch_bounds__(512, 2) void attn_k(const bf16_t* __restrict__ Qh,
                                                 const bf16_t* __restrict__ Kh,
                                                 const bf16_t* __restrict__ VhT,
                                                 const float* __restrict__ vsp,
                                                 bf16_t* __restrict__ attn)
{
    __shared__ bf16_t Qs[8192];           // [2 half][128][32], lives A+B
    __shared__ float mr_sh[128];          // row max * SCALE, A -> B
    __shared__ __align__(16) char uni[35328];  // phase-exclusive union

    // phase A views
    bf16_t* KsB = (bf16_t*)uni;                       // 4 x [2][64][32] = 32768 B
    float*  msh = (float*)(uni + 32768);              // [8 wave][4 it][16] = 2048 B
    // phase B views
    bf16_t* Ks2 = (bf16_t*)uni;                       // [2][64][32]     = 8192 B
    bf16_t* VtL = (bf16_t*)(uni + 8192);              // [64 d][64 j] swz = 8192 B
    bf16_t* Ws  = (bf16_t*)(uni + 16384);             // [128][72]       = 18432 B
    float*  zsh = (float*)(uni + 34816);              // [8][16]         = 512 B

    const int tid = threadIdx.x;
    const int lane = tid & 63, wid = tid >> 6;        // 8 waves
    const int l15 = lane & 15, quad = lane >> 4;

    const int f = blockIdx.x;
    const int seq = f >> 3;
    const int bh = (f & 7) + 8 * (seq >> 4);   // XCD-locality
    const int i0 = (seq & 15) * 128;
    const int b = bh >> 4, h = bh & 15;
    const bf16_t* Qb  = Qh  + (size_t)bh * 131072;
    const bf16_t* Kb  = Kh  + (size_t)bh * 131072;
    const bf16_t* VbT = VhT + (size_t)bh * 131072;

    const int ssw = SRC_SWZ8(lane);
    const int rs  = RD_SWZ8(quad, l15);

    // ======================= phase A: full-row max =========================
    // stage Q [2][128][32] (16 granules, 2/wave)
#pragma unroll
    for (int c = 0; c < 2; ++c) {
        const int gg = wid * 2 + c;
        const int half = gg >> 3;
        const int row = (gg & 7) * 16 + (lane >> 2);
        gl2lds16(Qb + (size_t)(i0 + row) * 64 + half * 32 + ssw, Qs + gg * 512);
    }
    // prologue: K chunks 0,1,2 into buffers 0,1,2 (1 gl2lds/thread/chunk)
#pragma unroll
    for (int p = 0; p < 3; ++p) {
        const int gg = wid;                           // 0..7
        const int half = gg >> 2;
        const int row = (gg & 3) * 16 + (lane >> 2);
        gl2lds16(Kb + (size_t)(p * 64 + row) * 64 + half * 32 + ssw,
                 KsB + p * 4096 + gg * 512);
    }
    __syncthreads();   // full drain: Q + chunks 0-2 resident

    // wave's 4 i-tiles: it = (wid&1)*4 + mt'
    const int itb = (wid & 1) * 4;
    const int jt  = wid >> 1;        // wave's j-tile within each 64-j chunk
    bf16x8 af[4][2];
#pragma unroll
    for (int mt = 0; mt < 4; ++mt)
#pragma unroll
        for (int ks = 0; ks < 2; ++ks)
            af[mt][ks] = *(const bf16x8*)&Qs[ks * 4096 + ((itb + mt) * 16 + l15) * 32 + rs];

    float vm[4];
#pragma unroll
    for (int mt = 0; mt < 4; ++mt) vm[mt] = -3.0e38f;

    for (int jc = 0; jc < 32; ++jc) {
        if (jc < 30) WAIT_VM2();        // own chunk-jc load landed (3 chunks deep)
        else if (jc == 30) WAIT_VM1();
        else WAIT_VM0();
        BARRIER();                      // all waves: jc landed; jc-1 compute done
        if (jc < 29) {
            const int sb = (jc + 3) & 3;
            const int gg = wid;
            const int half = gg >> 2;
            const int row = (gg & 3) * 16 + (lane >> 2);
            gl2lds16(Kb + (size_t)((jc + 3) * 64 + row) * 64 + half * 32 + ssw,
                     KsB + sb * 4096 + gg * 512);
        }
        const int cb = jc & 3;
        const bf16x8 b0 = *(const bf16x8*)&KsB[cb * 4096 + (jt * 16 + l15) * 32 + rs];
        const bf16x8 b1 = *(const bf16x8*)&KsB[cb * 4096 + 2048 + (jt * 16 + l15) * 32 + rs];
#pragma unroll
        for (int mt = 0; mt < 4; ++mt) {
            f32x4 t = (f32x4){0.f, 0.f, 0.f, 0.f};
            t = MFMA_B16(b0, af[mt][0], t);   // lane = i, regs = j
            t = MFMA_B16(b1, af[mt][1], t);
            const float u = fmaxf(fmaxf(t[0], t[1]), t[2]);      // v_max3
            vm[mt] = fmaxf(fmaxf(u, t[3]), vm[mt]);              // v_max3
        }
    }

    // per-wave partial -> msh
#pragma unroll
    for (int mt = 0; mt < 4; ++mt) {
        float v = vm[mt];
        v = fmaxf(v, __shfl_xor(v, 16));
        v = fmaxf(v, __shfl_xor(v, 32));
        if (quad == 0) msh[wid * 64 + mt * 16 + l15] = v;
    }
    __syncthreads();

    // cross-wave combine -> mr_sh: row i = mt*16+il covered by waves
    // w = 2*jtx + (mt>>2), jtx in [0,4), local i-tile idx mt&3.
    if (tid < 128) {
        const int mt = tid >> 4, il = tid & 15;
        const int p = mt >> 2, lt = mt & 3;
        const float v = fmaxf(fmaxf(msh[(0 + p) * 64 + lt * 16 + il],
                                    msh[(2 + p) * 64 + lt * 16 + il]),
                              fmaxf(msh[(4 + p) * 64 + lt * 16 + il],
                                    msh[(6 + p) * 64 + lt * 16 + il]));
        mr_sh[tid] = v * SCALE;
    }
    __syncthreads();   // mr_sh visible; ALL phase-A union reads complete

    // ======================= phase B: banded attention =====================
    // wave owns i-tile mt = wid
    bf16x8 aq[2];
#pragma unroll
    for (int ks = 0; ks < 2; ++ks)
        aq[ks] = *(const bf16x8*)&Qs[ks * 4096 + (wid * 16 + l15) * 32 + rs];

    float mreg[4];
#pragma unroll
    for (int r = 0; r < 4; ++r)
        mreg[r] = mr_sh[wid * 16 + quad * 4 + r];

    f32x4 vsd4[4];
#pragma unroll
    for (int dt = 0; dt < 4; ++dt)
        vsd4[dt] = *(const f32x4*)&vsp[bh * 64 + dt * 16 + quad * 4];

    f32x4 accO[4];
#pragma unroll
    for (int dt = 0; dt < 4; ++dt) accO[dt] = (f32x4){0.f, 0.f, 0.f, 0.f};
    float zp[4] = {0.f, 0.f, 0.f, 0.f};

    for (int cb2 = 0; cb2 < 6; ++cb2) {
        const int jb = i0 - 128 + cb2 * 64;
        if (jb < 0 || jb >= S_) continue;  // block-uniform

        __syncthreads();                   // prior chunk's Ks2/VtL readers done
        // K chunk (slot-swizzled): 8 granules, 1/wave
        {
            const int gg = wid;
            const int half = gg >> 2;
            const int row = (gg & 3) * 16 + (lane >> 2);
            gl2lds16(Kb + (size_t)(jb + row) * 64 + half * 32 + ssw, Ks2 + gg * 512);
        }
        // V chunk from VhT: [64 d][64 j], phys slot p holds logical p^(d&7).
        {
            const int gg = wid;
            const int d = gg * 8 + (lane >> 3);
            const int jl = (lane & 7) ^ ((lane >> 3) & 7);
            gl2lds16(VbT + (size_t)d * 2048 + jb + jl * 8, VtL + gg * 512);
        }
        __syncthreads();

        // QK^T + exp weights (wave's own 16 i-rows)
#pragma unroll
        for (int jt4 = 0; jt4 < 4; ++jt4) {
            const bf16x8 k0 = *(const bf16x8*)&Ks2[(jt4 * 16 + l15) * 32 + rs];
            const bf16x8 k1 = *(const bf16x8*)&Ks2[2048 + (jt4 * 16 + l15) * 32 + rs];
            f32x4 sc = (f32x4){0.f, 0.f, 0.f, 0.f};
            sc = MFMA_B16(aq[0], k0, sc);   // lane = j, regs = i
            sc = MFMA_B16(aq[1], k1, sc);
#pragma unroll
            for (int r = 0; r < 4; ++r) {
                const int ig = i0 + wid * 16 + quad * 4 + r;
                const int jg = jb + jt4 * 16 + l15;
                const int dd = jg - ig;
                const bool ok = (dd >= -128) && (dd <= 127);
                const float e1 = __expf(sc[r] * SCALE - mreg[r]);
                const float wv = ok ? (__expf(e1) - 1.0f) : 0.0f;
                const bf16_t wb = (bf16_t)wv;
                zp[r] += (float)wb;
                Ws[(wid * 16 + quad * 4 + r) * 72 + jt4 * 16 + l15] = wb;
            }
        }
        // NO barrier: Ws rows [wid*16, wid*16+16) are wave-private (write and
        // read below); VtL was drained by the post-staging __syncthreads.

        // PV
#pragma unroll
        for (int ks = 0; ks < 2; ++ks) {
            bf16x8 bv[4];
#pragma unroll
            for (int dt = 0; dt < 4; ++dt)
                bv[dt] = *(const bf16x8*)&VtL[(dt * 16 + l15) * 64 +
                                              (((ks * 4 + quad) ^ (l15 & 7)) * 8)];
            const bf16x8 aw = *(const bf16x8*)&Ws[(wid * 16 + l15) * 72 + ks * 32 + quad * 8];
#pragma unroll
            for (int dt = 0; dt < 4; ++dt)
                accO[dt] = MFMA_B16(bv[dt], aw, accO[dt]);  // lane=i, regs=d
        }
    }

#pragma unroll
    for (int r = 0; r < 4; ++r) {
        float z = zp[r];
        z += __shfl_xor(z, 1);
        z += __shfl_xor(z, 2);
        z += __shfl_xor(z, 4);
        z += __shfl_xor(z, 8);
        if (l15 == 0) zsh[wid * 16 + quad * 4 + r] = z + (float)S_;
    }
    __syncthreads();

    {
        const float rz = 1.0f / zsh[wid * 16 + l15];
        const int irow = i0 + wid * 16 + l15;
#pragma unroll
        for (int dt = 0; dt < 4; ++dt) {
            bf16x4 o;
#pragma unroll
            for (int r = 0; r < 4; ++r)
                o[r] = (bf16_t)((accO[dt][r] + vsd4[dt][r]) * rz);
            *(bf16x4*)&attn[(size_t)(b * S_ + irow) * 1024 + h * 64 + dt * 16 + quad * 4] = o;
        }
    }
}

// ---------------------------------------------------------------------------
// Launch: 4 kernels
// ---------------------------------------------------------------------------
extern "C" void kernel_launch(void* const* d_in, const int* in_sizes, int n_in,
                              void* d_out, int out_size, void* d_ws, size_t ws_size,
                              hipStream_t stream)
{
    const float* x  = (const float*)d_in[0];
    const float* Wq = (const float*)d_in[1];
    const float* Wk = (const float*)d_in[2];
    const float* Wv = (const float*)d_in[3];
    const float* Wo = (const float*)d_in[4];
    float* out = (float*)d_out;

    char* ws = (char*)d_ws;
    bf16_t* xb   = (bf16_t*)(ws + 0);
    bf16_t* Wqt  = (bf16_t*)(ws + 8388608);
    bf16_t* Wkt  = (bf16_t*)(ws + 10485760);
    bf16_t* Wvt  = (bf16_t*)(ws + 12582912);
    bf16_t* Wot  = (bf16_t*)(ws + 14680064);
    bf16_t* Qh   = (bf16_t*)(ws + 16777216);   // [bh][s][64]
    bf16_t* Kh   = (bf16_t*)(ws + 25165824);   // [bh][s][64]
    bf16_t* VhT  = (bf16_t*)(ws + 33554432);   // [bh][d][s]  (V transposed)
    bf16_t* attn = (bf16_t*)(ws + 41943040);   // [m][1024]
    float*  vsp  = (float*)(ws + 50331648);    // [bh][64] f32, zeroed by prep

    prep<<<2049, 256, 0, stream>>>(x, Wq, Wk, Wv, Wo, xb, Wqt, Wkt, Wvt, Wot, vsp);
    gemm_qkv_mfma<<<dim3(8, 32, 3), 256, 0, stream>>>(xb, Wqt, Wkt, Wvt, Qh, Kh, VhT, vsp);
    attn_k<<<512, 512, 0, stream>>>(Qh, Kh, VhT, vsp, attn);
    gemm_out_mfma<<<dim3(8, 32), 256, 0, stream>>>(attn, Wot, out);
}

// Round 10
// 220.649 us; speedup vs baseline: 1.3538x; 1.0296x over previous
//
#include <hip/hip_runtime.h>
#include <math.h>

typedef __bf16 bf16_t;
typedef bf16_t bf16x8 __attribute__((ext_vector_type(8)));
typedef bf16_t bf16x4 __attribute__((ext_vector_type(4)));
typedef float f32x4 __attribute__((ext_vector_type(4)));

constexpr int S_ = 2048;
constexpr float SCALE = 0.125f;  // 1/sqrt(64)

#define MFMA_B16(a, b, c) __builtin_amdgcn_mfma_f32_16x16x32_bf16(a, b, c, 0, 0, 0)

// s_waitcnt immediates (gfx9 enc): [3:0]=vmcnt_lo, [6:4]=expcnt, [12:8]=lgkmcnt
#define WAIT_VM0() __builtin_amdgcn_s_waitcnt(0x0F70)
#define WAIT_VM2() __builtin_amdgcn_s_waitcnt(0x0F72)
#define WAIT_VM4() __builtin_amdgcn_s_waitcnt(0x0F74)
#define BARRIER()  __builtin_amdgcn_s_barrier()

typedef __attribute__((address_space(1))) const void* as1_cvp;
typedef __attribute__((address_space(3))) void* as3_vp;

__device__ __forceinline__ void gl2lds16(const void* g, void* l)
{
    __builtin_amdgcn_global_load_lds((as1_cvp)g, (as3_vp)l, 16, 0, 0);
}

// ---------------------------------------------------------------------------
// LDS slot swizzle for row-major [*][32]bf16 tiles (64B rows, 4x16B slots):
//   slot' = slot ^ ((row>>1)&3)
// Linear LDS dest (global_load_lds requirement) + pre-swizzled global source
// column; fragment reads apply the same XOR. 2-way (free) bank aliasing.
// ---------------------------------------------------------------------------
#define SRC_SWZ8(lane) ((((lane) & 3) ^ (((lane) >> 3) & 3)) * 8)
#define RD_SWZ8(quad, l15) ((((quad) ^ (((l15) >> 1) & 3))) * 8)

// ---------------------------------------------------------------------------
// prep: cast x -> bf16 (blocks 0..1023), transpose-cast 4 weights (1024..2047),
// zero vsp (block 2048)
// ---------------------------------------------------------------------------
__global__ __launch_bounds__(256) void prep(const float* __restrict__ x,
                                            const float* __restrict__ Wq,
                                            const float* __restrict__ Wk,
                                            const float* __restrict__ Wv,
                                            const float* __restrict__ Wo,
                                            bf16_t* __restrict__ xb,
                                            bf16_t* __restrict__ Wqt,
                                            bf16_t* __restrict__ Wkt,
                                            bf16_t* __restrict__ Wvt,
                                            bf16_t* __restrict__ Wot,
                                            float* __restrict__ vsp)
{
    __shared__ float T[64][65];
    const int blk = blockIdx.x;
    const int tid = threadIdx.x;
    if (blk < 1024) {
#pragma unroll
        for (int u = 0; u < 4; ++u) {
            const int g = blk * 1024 + u * 256 + tid;
            const float4 v = ((const float4*)x)[g];
            bf16x4 o;
            o[0] = (bf16_t)v.x; o[1] = (bf16_t)v.y;
            o[2] = (bf16_t)v.z; o[3] = (bf16_t)v.w;
            *(bf16x4*)&xb[(size_t)g * 4] = o;
        }
    } else if (blk < 2048) {
        const int rem = blk - 1024;
        const int wsel = rem >> 8, t = rem & 255;
        const float* src = (wsel == 0) ? Wq : (wsel == 1) ? Wk : (wsel == 2) ? Wv : Wo;
        bf16_t* dst = (wsel == 0) ? Wqt : (wsel == 1) ? Wkt : (wsel == 2) ? Wvt : Wot;
        const int k0 = (t >> 4) * 64, n0 = (t & 15) * 64;
        const int rr = tid >> 4, c4 = (tid & 15) * 4;
#pragma unroll
        for (int u = 0; u < 4; ++u) {
            const float4 v = *(const float4*)&src[(size_t)(k0 + u * 16 + rr) * 1024 + n0 + c4];
            T[u * 16 + rr][c4 + 0] = v.x; T[u * 16 + rr][c4 + 1] = v.y;
            T[u * 16 + rr][c4 + 2] = v.z; T[u * 16 + rr][c4 + 3] = v.w;
        }
        __syncthreads();
#pragma unroll
        for (int u = 0; u < 4; ++u) {
            bf16x4 o;
#pragma unroll
            for (int e = 0; e < 4; ++e) o[e] = (bf16_t)T[c4 + e][u * 16 + rr];
            *(bf16x4*)&dst[(size_t)(n0 + u * 16 + rr) * 1024 + k0 + c4] = o;
        }
    } else {
#pragma unroll
        for (int u = 0; u < 8; ++u) vsp[u * 256 + tid] = 0.f;
    }
}

// ---------------------------------------------------------------------------
// bf16 MFMA GEMM, tri-buffered, fully unrolled K-loop (static buffer indices).
// 2 tiles in flight, vmcnt(4) retires only the older. LDS slot-swizzled.
// MODE 0: f32 store to dst[m][1024].
// MODE 1: bf16 store to [bh][s][64] (Q/K heads layout).
// MODE 2: bf16 store TRANSPOSED to VhT[bh][d][s] (A=Wvt, Bt=xb: m=hd, n=s)
//         + vsum (sum over s of V) from f32 acc.
// ---------------------------------------------------------------------------
template <int MODE>
__device__ __forceinline__ void mfma_gemm_body(bf16_t* __restrict__ As,
                                               bf16_t* __restrict__ Bs,
                                               const bf16_t* __restrict__ A,
                                               const bf16_t* __restrict__ Bt,
                                               void* __restrict__ dst,
                                               float* __restrict__ vsum_out,
                                               int m0, int n0)
{
    const int tid = threadIdx.x;
    const int lane = tid & 63, wid = tid >> 6;
    const int l15 = lane & 15, quad = lane >> 4;
    const int wm = (wid & 1) * 64, wn = (wid >> 1) * 64;

    const int srow = wid * 32 + (lane >> 2);
    const int scg8 = SRC_SWZ8(lane);   // pre-swizzled source slot
    const bf16_t* Ag0 = A  + (size_t)(m0 + srow) * 1024 + scg8;
    const bf16_t* Ag1 = A  + (size_t)(m0 + srow + 16) * 1024 + scg8;
    const bf16_t* Bg0 = Bt + (size_t)(n0 + srow) * 1024 + scg8;
    const bf16_t* Bg1 = Bt + (size_t)(n0 + srow + 16) * 1024 + scg8;

    const int rs = RD_SWZ8(quad, l15); // swizzled read slot

    f32x4 acc[4][4];
#pragma unroll
    for (int i = 0; i < 4; ++i)
#pragma unroll
        for (int j = 0; j < 4; ++j) acc[i][j] = (f32x4){0.f, 0.f, 0.f, 0.f};

    // prologue: tiles 0,1 into buffers 0,1
#pragma unroll
    for (int p = 0; p < 2; ++p) {
        const int k0 = p * 32;
        gl2lds16(Ag0 + k0, As + p * 4096 + (wid * 2 + 0) * 512);
        gl2lds16(Ag1 + k0, As + p * 4096 + (wid * 2 + 1) * 512);
        gl2lds16(Bg0 + k0, Bs + p * 4096 + (wid * 2 + 0) * 512);
        gl2lds16(Bg1 + k0, Bs + p * 4096 + (wid * 2 + 1) * 512);
    }

#pragma unroll
    for (int it = 0; it < 32; ++it) {
        if (it < 30) WAIT_VM4(); else WAIT_VM0();
        BARRIER();
        if (it < 30) {
            const int k0 = (it + 2) * 32;
            const int sb = (it + 2) % 3;          // compile-time after unroll
            gl2lds16(Ag0 + k0, As + sb * 4096 + (wid * 2 + 0) * 512);
            gl2lds16(Ag1 + k0, As + sb * 4096 + (wid * 2 + 1) * 512);
            gl2lds16(Bg0 + k0, Bs + sb * 4096 + (wid * 2 + 0) * 512);
            gl2lds16(Bg1 + k0, Bs + sb * 4096 + (wid * 2 + 1) * 512);
        }
        const int cb = it % 3;                    // compile-time after unroll
        bf16x8 af[4], bfr[4];
#pragma unroll
        for (int mt = 0; mt < 4; ++mt)
            af[mt] = *(const bf16x8*)&As[cb * 4096 + (wm + mt * 16 + l15) * 32 + rs];
#pragma unroll
        for (int nt = 0; nt < 4; ++nt)
            bfr[nt] = *(const bf16x8*)&Bs[cb * 4096 + (wn + nt * 16 + l15) * 32 + rs];
#pragma unroll
        for (int mt = 0; mt < 4; ++mt)
#pragma unroll
            for (int nt = 0; nt < 4; ++nt)
                acc[mt][nt] = MFMA_B16(bfr[nt], af[mt], acc[mt][nt]);  // lane=m, regs=n
    }

#pragma unroll
    for (int mt = 0; mt < 4; ++mt) {
        const int m = m0 + wm + mt * 16 + l15;
#pragma unroll
        for (int nt = 0; nt < 4; ++nt) {
            const int nb = n0 + wn + nt * 16 + quad * 4;
            if (MODE == 0) {
                *(f32x4*)&((float*)dst)[(size_t)m * 1024 + nb] = acc[mt][nt];
            } else if (MODE == 1) {
                const int bb = m >> 11, s = m & 2047;
                const int hh = nb >> 6, d = nb & 63;
                bf16x4 o;
#pragma unroll
                for (int u = 0; u < 4; ++u) o[u] = (bf16_t)acc[mt][nt][u];
                *(bf16x4*)&((bf16_t*)dst)[((size_t)(bb * 16 + hh) * 2048 + s) * 64 + d] = o;
            } else {
                // MODE 2: m = hd, n = s; store V^T[bh][d][s] contiguous in s
                const int bb = n0 >> 11;          // n-tile (128) within one bb
                const int hh = m >> 6, dd = m & 63;
                bf16x4 o;
#pragma unroll
                for (int u = 0; u < 4; ++u) o[u] = (bf16_t)acc[mt][nt][u];
                *(bf16x4*)&((bf16_t*)dst)[((size_t)(bb * 16 + hh) * 64 + dd) * 2048 + (nb & 2047)] = o;
            }
        }
    }

    if (MODE == 2 && vsum_out != nullptr) {
        const int bb = n0 >> 11;
#pragma unroll
        for (int mt = 0; mt < 4; ++mt) {
            float p = 0.f;
#pragma unroll
            for (int nt = 0; nt < 4; ++nt)
                p += acc[mt][nt][0] + acc[mt][nt][1] + acc[mt][nt][2] + acc[mt][nt][3];
            p += __shfl_xor(p, 16);   // reduce over quad (s sub-range)
            p += __shfl_xor(p, 32);
            if (quad == 0) {
                const int m = m0 + wm + mt * 16 + l15;   // hd
                atomicAdd(&vsum_out[(bb * 16 + (m >> 6)) * 64 + (m & 63)], p);
            }
        }
    }
}

// L2-aware remap: HW XCD = dispatch_linear % 8 = blockIdx.x. Each XCD owns a
// contiguous panel strip so A+B working set fits the 4 MB per-XCD L2.
__device__ __forceinline__ int remap_m(void) { return (blockIdx.x << 2) + (blockIdx.y >> 3); }
__device__ __forceinline__ int remap_n(void) { return blockIdx.y & 7; }

__global__ __launch_bounds__(256) void gemm_qkv_mfma(const bf16_t* __restrict__ xb,
                                                     const bf16_t* __restrict__ Wqt,
                                                     const bf16_t* __restrict__ Wkt,
                                                     const bf16_t* __restrict__ Wvt,
                                                     bf16_t* Qh, bf16_t* Kh, bf16_t* VhT,
                                                     float* vsp)
{
    __shared__ bf16_t As[12288];  // 3 x [128][32], slot-swizzled (shared by both paths)
    __shared__ bf16_t Bs[12288];
    if (blockIdx.z == 2) {
        // V^T GEMM: m-dim = hd (8 tiles), n-dim = s (32 tiles); swap remaps so
        // XCD x gets an s-strip (1MB xb) + full Wvt (2MB) -> L2-resident.
        mfma_gemm_body<2>(As, Bs, Wvt, xb, VhT, vsp, remap_n() * 128, remap_m() * 128);
    } else {
        const bf16_t* Bt = (blockIdx.z == 0) ? Wqt : Wkt;
        bf16_t* dst = (blockIdx.z == 0) ? Qh : Kh;
        mfma_gemm_body<1>(As, Bs, xb, Bt, dst, nullptr, remap_m() * 128, remap_n() * 128);
    }
}

__global__ __launch_bounds__(256) void gemm_out_mfma(const bf16_t* __restrict__ attn,
                                                     const bf16_t* __restrict__ Wot,
                                                     float* __restrict__ out)
{
    __shared__ bf16_t As[12288];
    __shared__ bf16_t Bs[12288];
    mfma_gemm_body<0>(As, Bs, attn, Wot, out, nullptr, remap_m() * 128, remap_n() * 128);
}

// ---------------------------------------------------------------------------
// Fused attention kernel, R10: 1024 blocks x 256 THREADS, 64 q-rows/block.
// R7's 48us kernel had grid 512 = 2 blocks/CU -> occupancy hard-capped at
// 8 waves/CU (25%); measured 17.5%, ~48% stall cycles. This round: finer
// split (proven 256-thread wave shapes, HALVED per-block state) -> LDS
// 34304 B -> 4 blocks/CU = 16 waves/CU = 4 waves/SIMD. No launch bound
// (R8/R9 lesson: min-waves bounds triggered catastrophic spill).
// Phase A: full-row max over 32 double-buffered 64-j chunks (WAIT_VM2
// ledger, R3-verified); wave = j-tile wid x 4 i-tiles (af[4][2]).
// Phase B: 5 band chunks of 64 j; wave owns i-tile wid; wave-private Ws
// (no QK->PV barrier, R9-verified); V from pre-transposed VhT (swizzled).
// Per-output op sequence identical to R7/R9 -> absmax unchanged.
// ---------------------------------------------------------------------------
__global__ __launch_bounds__(256) void attn_k(const bf16_t* __restrict__ Qh,
                                              const bf16_t* __restrict__ Kh,
                                              const bf16_t* __restrict__ VhT,
                                              const float* __restrict__ vsp,
                                              bf16_t* __restrict__ attn)
{
    __shared__ bf16_t Qs[4096];           // [2 half][64][32] = 8192 B, lives A+B
    __shared__ float mr_sh[64];           // row max * SCALE, A -> B (256 B)
    __shared__ __align__(16) char uni[25856];  // phase-exclusive union

    // phase A views
    bf16_t* KsA = (bf16_t*)uni;                       // 2 x [2][64][32] = 16384 B
    float*  msh = (float*)(uni + 16384);              // [4 wave][4 it][16] = 1024 B
    // phase B views
    bf16_t* Ks2 = (bf16_t*)uni;                       // [2][64][32]     = 8192 B
    bf16_t* VtL = (bf16_t*)(uni + 8192);              // [64 d][64 j] swz = 8192 B
    bf16_t* Ws  = (bf16_t*)(uni + 16384);             // [64][72]        = 9216 B
    float*  zsh = (float*)(uni + 25600);              // [4][16]         = 256 B

    const int tid = threadIdx.x;
    const int lane = tid & 63, wid = tid >> 6;        // 4 waves
    const int l15 = lane & 15, quad = lane >> 4;

    const int f = blockIdx.x;                          // 1024 blocks
    const int seq = f >> 3;                            // [0,128)
    const int bh = (f & 7) + 8 * (seq >> 5);           // XCD-locality, [0,32)
    const int i0 = (seq & 31) * 64;                    // 64-row q block
    const int b = bh >> 4, h = bh & 15;
    const bf16_t* Qb  = Qh  + (size_t)bh * 131072;
    const bf16_t* Kb  = Kh  + (size_t)bh * 131072;
    const bf16_t* VbT = VhT + (size_t)bh * 131072;

    const int ssw = SRC_SWZ8(lane);
    const int rs  = RD_SWZ8(quad, l15);

    // ======================= phase A: full-row max =========================
    // stage Q [2][64][32] (8 granules, 2/wave)
#pragma unroll
    for (int c = 0; c < 2; ++c) {
        const int gg = wid * 2 + c;
        const int half = gg >> 2;
        const int row = (gg & 3) * 16 + (lane >> 2);
        gl2lds16(Qb + (size_t)(i0 + row) * 64 + half * 32 + ssw, Qs + gg * 512);
    }
    // K chunk 0 -> buf 0 (2/thread)
#pragma unroll
    for (int c = 0; c < 2; ++c) {
        const int gg = wid * 2 + c;
        const int half = gg >> 2;
        const int row = (gg & 3) * 16 + (lane >> 2);
        gl2lds16(Kb + (size_t)row * 64 + half * 32 + ssw, KsA + gg * 512);
    }
    __syncthreads();   // full drain: Q + chunk 0 resident

    bf16x8 af[4][2];
#pragma unroll
    for (int mt = 0; mt < 4; ++mt)
#pragma unroll
        for (int ks = 0; ks < 2; ++ks)
            af[mt][ks] = *(const bf16x8*)&Qs[ks * 2048 + (mt * 16 + l15) * 32 + rs];

    float vm[4];
#pragma unroll
    for (int mt = 0; mt < 4; ++mt) vm[mt] = -3.0e38f;

    for (int jc = 0; jc < 32; ++jc) {
        BARRIER();                      // readers of buf we overwrite are done
        if (jc < 31) {
            const int sb = (jc + 1) & 1;
#pragma unroll
            for (int c = 0; c < 2; ++c) {
                const int gg = wid * 2 + c;
                const int half = gg >> 2;
                const int row = (gg & 3) * 16 + (lane >> 2);
                gl2lds16(Kb + (size_t)((jc + 1) * 64 + row) * 64 + half * 32 + ssw,
                         KsA + sb * 4096 + gg * 512);
            }
            WAIT_VM2();                 // retire chunk jc's 2, keep jc+1 in flight
        } else {
            WAIT_VM0();
        }
        BARRIER();                      // all waves: chunk jc visible

        const int cb = jc & 1;
        // wave's j-tile = wid (PARTIAL over j; cross-wave combine via msh)
        const bf16x8 b0 = *(const bf16x8*)&KsA[cb * 4096 + (wid * 16 + l15) * 32 + rs];
        const bf16x8 b1 = *(const bf16x8*)&KsA[cb * 4096 + 2048 + (wid * 16 + l15) * 32 + rs];
#pragma unroll
        for (int mt = 0; mt < 4; ++mt) {
            f32x4 t = (f32x4){0.f, 0.f, 0.f, 0.f};
            t = MFMA_B16(b0, af[mt][0], t);   // lane = i, regs = j
            t = MFMA_B16(b1, af[mt][1], t);
            const float u = fmaxf(fmaxf(t[0], t[1]), t[2]);      // v_max3
            vm[mt] = fmaxf(fmaxf(u, t[3]), vm[mt]);              // v_max3
        }
    }

    // per-wave partial -> msh
#pragma unroll
    for (int mt = 0; mt < 4; ++mt) {
        float v = vm[mt];
        v = fmaxf(v, __shfl_xor(v, 16));
        v = fmaxf(v, __shfl_xor(v, 32));
        if (quad == 0) msh[(wid * 4 + mt) * 16 + l15] = v;
    }
    __syncthreads();

    // cross-wave combine -> mr_sh (row r = tid for tid<64)
    if (tid < 64) {
        const int mt = tid >> 4, il = tid & 15;
        const float v = fmaxf(fmaxf(msh[(0 * 4 + mt) * 16 + il], msh[(1 * 4 + mt) * 16 + il]),
                              fmaxf(msh[(2 * 4 + mt) * 16 + il], msh[(3 * 4 + mt) * 16 + il]));
        mr_sh[tid] = v * SCALE;
    }
    __syncthreads();   // mr_sh visible; ALL phase-A union reads complete

    // ======================= phase B: banded attention =====================
    // wave owns i-tile wid
    bf16x8 aq[2];
#pragma unroll
    for (int ks = 0; ks < 2; ++ks)
        aq[ks] = *(const bf16x8*)&Qs[ks * 2048 + (wid * 16 + l15) * 32 + rs];

    float mreg[4];
#pragma unroll
    for (int r = 0; r < 4; ++r)
        mreg[r] = mr_sh[wid * 16 + quad * 4 + r];

    f32x4 vsd4[4];
#pragma unroll
    for (int dt = 0; dt < 4; ++dt)
        vsd4[dt] = *(const f32x4*)&vsp[bh * 64 + dt * 16 + quad * 4];

    f32x4 accO[4];
#pragma unroll
    for (int dt = 0; dt < 4; ++dt) accO[dt] = (f32x4){0.f, 0.f, 0.f, 0.f};
    float zp[4] = {0.f, 0.f, 0.f, 0.f};

    for (int cb2 = 0; cb2 < 5; ++cb2) {
        const int jb = i0 - 128 + cb2 * 64;
        if (jb < 0 || jb >= S_) continue;  // block-uniform

        __syncthreads();                   // prior chunk's Ks2/VtL readers done
        // K chunk (slot-swizzled): 8 granules, 2/wave
#pragma unroll
        for (int c = 0; c < 2; ++c) {
            const int gg = wid * 2 + c;
            const int half = gg >> 2;
            const int row = (gg & 3) * 16 + (lane >> 2);
            gl2lds16(Kb + (size_t)(jb + row) * 64 + half * 32 + ssw, Ks2 + gg * 512);
        }
        // V chunk from VhT: [64 d][64 j], phys slot p holds logical p^(d&7).
#pragma unroll
        for (int c = 0; c < 2; ++c) {
            const int gg = wid * 2 + c;               // granule: 8 d-rows
            const int d = gg * 8 + (lane >> 3);
            const int jl = (lane & 7) ^ ((lane >> 3) & 7);
            gl2lds16(VbT + (size_t)d * 2048 + jb + jl * 8, VtL + gg * 512);
        }
        __syncthreads();

        // QK^T + exp weights (wave's own 16 i-rows)
#pragma unroll
        for (int jt4 = 0; jt4 < 4; ++jt4) {
            const bf16x8 k0 = *(const bf16x8*)&Ks2[(jt4 * 16 + l15) * 32 + rs];
            const bf16x8 k1 = *(const bf16x8*)&Ks2[2048 + (jt4 * 16 + l15) * 32 + rs];
            f32x4 sc = (f32x4){0.f, 0.f, 0.f, 0.f};
            sc = MFMA_B16(aq[0], k0, sc);   // lane = j, regs = i
            sc = MFMA_B16(aq[1], k1, sc);
#pragma unroll
            for (int r = 0; r < 4; ++r) {
                const int ig = i0 + wid * 16 + quad * 4 + r;
                const int jg = jb + jt4 * 16 + l15;
                const int dd = jg - ig;
                const bool ok = (dd >= -128) && (dd <= 127);
                const float e1 = __expf(sc[r] * SCALE - mreg[r]);
                const float wv = ok ? (__expf(e1) - 1.0f) : 0.0f;
                const bf16_t wb = (bf16_t)wv;
                zp[r] += (float)wb;
                Ws[(wid * 16 + quad * 4 + r) * 72 + jt4 * 16 + l15] = wb;
            }
        }
        // NO barrier: Ws rows [wid*16, wid*16+16) are wave-private (write and
        // read below); VtL was drained by the post-staging __syncthreads.

        // PV
#pragma unroll
        for (int ks = 0; ks < 2; ++ks) {
            bf16x8 bv[4];
#pragma unroll
            for (int dt = 0; dt < 4; ++dt)
                bv[dt] = *(const bf16x8*)&VtL[(dt * 16 + l15) * 64 +
                                              (((ks * 4 + quad) ^ (l15 & 7)) * 8)];
            const bf16x8 aw = *(const bf16x8*)&Ws[(wid * 16 + l15) * 72 + ks * 32 + quad * 8];
#pragma unroll
            for (int dt = 0; dt < 4; ++dt)
                accO[dt] = MFMA_B16(bv[dt], aw, accO[dt]);  // lane=i, regs=d
        }
    }

#pragma unroll
    for (int r = 0; r < 4; ++r) {
        float z = zp[r];
        z += __shfl_xor(z, 1);
        z += __shfl_xor(z, 2);
        z += __shfl_xor(z, 4);
        z += __shfl_xor(z, 8);
        if (l15 == 0) zsh[wid * 16 + quad * 4 + r] = z + (float)S_;
    }
    __syncthreads();

    {
        const float rz = 1.0f / zsh[wid * 16 + l15];
        const int irow = i0 + wid * 16 + l15;
#pragma unroll
        for (int dt = 0; dt < 4; ++dt) {
            bf16x4 o;
#pragma unroll
            for (int r = 0; r < 4; ++r)
                o[r] = (bf16_t)((accO[dt][r] + vsd4[dt][r]) * rz);
            *(bf16x4*)&attn[(size_t)(b * S_ + irow) * 1024 + h * 64 + dt * 16 + quad * 4] = o;
        }
    }
}

// ---------------------------------------------------------------------------
// Launch: 4 kernels
// ---------------------------------------------------------------------------
extern "C" void kernel_launch(void* const* d_in, const int* in_sizes, int n_in,
                              void* d_out, int out_size, void* d_ws, size_t ws_size,
                              hipStream_t stream)
{
    const float* x  = (const float*)d_in[0];
    const float* Wq = (const float*)d_in[1];
    const float* Wk = (const float*)d_in[2];
    const float* Wv = (const float*)d_in[3];
    const float* Wo = (const float*)d_in[4];
    float* out = (float*)d_out;

    char* ws = (char*)d_ws;
    bf16_t* xb   = (bf16_t*)(ws + 0);
    bf16_t* Wqt  = (bf16_t*)(ws + 8388608);
    bf16_t* Wkt  = (bf16_t*)(ws + 10485760);
    bf16_t* Wvt  = (bf16_t*)(ws + 12582912);
    bf16_t* Wot  = (bf16_t*)(ws + 14680064);
    bf16_t* Qh   = (bf16_t*)(ws + 16777216);   // [bh][s][64]
    bf16_t* Kh   = (bf16_t*)(ws + 25165824);   // [bh][s][64]
    bf16_t* VhT  = (bf16_t*)(ws + 33554432);   // [bh][d][s]  (V transposed)
    bf16_t* attn = (bf16_t*)(ws + 41943040);   // [m][1024]
    float*  vsp  = (float*)(ws + 50331648);    // [bh][64] f32, zeroed by prep

    prep<<<2049, 256, 0, stream>>>(x, Wq, Wk, Wv, Wo, xb, Wqt, Wkt, Wvt, Wot, vsp);
    gemm_qkv_mfma<<<dim3(8, 32, 3), 256, 0, stream>>>(xb, Wqt, Wkt, Wvt, Qh, Kh, VhT, vsp);
    attn_k<<<1024, 256, 0, stream>>>(Qh, Kh, VhT, vsp, attn);
    gemm_out_mfma<<<dim3(8, 32), 256, 0, stream>>>(attn, Wot, out);
}

// Round 11
// 180.245 us; speedup vs baseline: 1.6573x; 1.2242x over previous
//
#include <hip/hip_runtime.h>
#include <math.h>

typedef __bf16 bf16_t;
typedef bf16_t bf16x8 __attribute__((ext_vector_type(8)));
typedef bf16_t bf16x4 __attribute__((ext_vector_type(4)));
typedef float f32x4 __attribute__((ext_vector_type(4)));

constexpr int S_ = 2048;
constexpr float SCALE = 0.125f;  // 1/sqrt(64)

#define MFMA_B16(a, b, c) __builtin_amdgcn_mfma_f32_16x16x32_bf16(a, b, c, 0, 0, 0)

// s_waitcnt immediates (gfx9 enc): [3:0]=vmcnt_lo, [6:4]=expcnt, [12:8]=lgkmcnt
#define WAIT_VM0() __builtin_amdgcn_s_waitcnt(0x0F70)
#define WAIT_VM1() __builtin_amdgcn_s_waitcnt(0x0F71)
#define WAIT_VM2() __builtin_amdgcn_s_waitcnt(0x0F72)
#define WAIT_VM4() __builtin_amdgcn_s_waitcnt(0x0F74)
#define BARRIER()  __builtin_amdgcn_s_barrier()

typedef __attribute__((address_space(1))) const void* as1_cvp;
typedef __attribute__((address_space(3))) void* as3_vp;

__device__ __forceinline__ void gl2lds16(const void* g, void* l)
{
    __builtin_amdgcn_global_load_lds((as1_cvp)g, (as3_vp)l, 16, 0, 0);
}

// ---------------------------------------------------------------------------
// LDS slot swizzle for row-major [*][32]bf16 tiles (64B rows, 4x16B slots):
//   slot' = slot ^ ((row>>1)&3)
// Linear LDS dest (global_load_lds requirement) + pre-swizzled global source
// column; fragment reads apply the same XOR. 2-way (free) bank aliasing.
// ---------------------------------------------------------------------------
#define SRC_SWZ8(lane) ((((lane) & 3) ^ (((lane) >> 3) & 3)) * 8)
#define RD_SWZ8(quad, l15) ((((quad) ^ (((l15) >> 1) & 3))) * 8)

// ---------------------------------------------------------------------------
// prep: cast x -> bf16 (blocks 0..1023), transpose-cast 4 weights (1024..2047),
// zero vsp (block 2048)
// ---------------------------------------------------------------------------
__global__ __launch_bounds__(256) void prep(const float* __restrict__ x,
                                            const float* __restrict__ Wq,
                                            const float* __restrict__ Wk,
                                            const float* __restrict__ Wv,
                                            const float* __restrict__ Wo,
                                            bf16_t* __restrict__ xb,
                                            bf16_t* __restrict__ Wqt,
                                            bf16_t* __restrict__ Wkt,
                                            bf16_t* __restrict__ Wvt,
                                            bf16_t* __restrict__ Wot,
                                            float* __restrict__ vsp)
{
    __shared__ float T[64][65];
    const int blk = blockIdx.x;
    const int tid = threadIdx.x;
    if (blk < 1024) {
#pragma unroll
        for (int u = 0; u < 4; ++u) {
            const int g = blk * 1024 + u * 256 + tid;
            const float4 v = ((const float4*)x)[g];
            bf16x4 o;
            o[0] = (bf16_t)v.x; o[1] = (bf16_t)v.y;
            o[2] = (bf16_t)v.z; o[3] = (bf16_t)v.w;
            *(bf16x4*)&xb[(size_t)g * 4] = o;
        }
    } else if (blk < 2048) {
        const int rem = blk - 1024;
        const int wsel = rem >> 8, t = rem & 255;
        const float* src = (wsel == 0) ? Wq : (wsel == 1) ? Wk : (wsel == 2) ? Wv : Wo;
        bf16_t* dst = (wsel == 0) ? Wqt : (wsel == 1) ? Wkt : (wsel == 2) ? Wvt : Wot;
        const int k0 = (t >> 4) * 64, n0 = (t & 15) * 64;
        const int rr = tid >> 4, c4 = (tid & 15) * 4;
#pragma unroll
        for (int u = 0; u < 4; ++u) {
            const float4 v = *(const float4*)&src[(size_t)(k0 + u * 16 + rr) * 1024 + n0 + c4];
            T[u * 16 + rr][c4 + 0] = v.x; T[u * 16 + rr][c4 + 1] = v.y;
            T[u * 16 + rr][c4 + 2] = v.z; T[u * 16 + rr][c4 + 3] = v.w;
        }
        __syncthreads();
#pragma unroll
        for (int u = 0; u < 4; ++u) {
            bf16x4 o;
#pragma unroll
            for (int e = 0; e < 4; ++e) o[e] = (bf16_t)T[c4 + e][u * 16 + rr];
            *(bf16x4*)&dst[(size_t)(n0 + u * 16 + rr) * 1024 + k0 + c4] = o;
        }
    } else {
#pragma unroll
        for (int u = 0; u < 8; ++u) vsp[u * 256 + tid] = 0.f;
    }
}

// ---------------------------------------------------------------------------
// bf16 MFMA GEMM, tri-buffered, fully unrolled K-loop (static buffer indices).
// 2 tiles in flight, vmcnt(4) retires only the older. LDS slot-swizzled.
// MODE 0: f32 store to dst[m][1024].
// MODE 1: bf16 store to [bh][s][64] (Q/K heads layout).
// MODE 2: bf16 store TRANSPOSED to VhT[bh][d][s] (A=Wvt, Bt=xb: m=hd, n=s)
//         + vsum (sum over s of V) from f32 acc.
// ---------------------------------------------------------------------------
template <int MODE>
__device__ __forceinline__ void mfma_gemm_body(bf16_t* __restrict__ As,
                                               bf16_t* __restrict__ Bs,
                                               const bf16_t* __restrict__ A,
                                               const bf16_t* __restrict__ Bt,
                                               void* __restrict__ dst,
                                               float* __restrict__ vsum_out,
                                               int m0, int n0)
{
    const int tid = threadIdx.x;
    const int lane = tid & 63, wid = tid >> 6;
    const int l15 = lane & 15, quad = lane >> 4;
    const int wm = (wid & 1) * 64, wn = (wid >> 1) * 64;

    const int srow = wid * 32 + (lane >> 2);
    const int scg8 = SRC_SWZ8(lane);   // pre-swizzled source slot
    const bf16_t* Ag0 = A  + (size_t)(m0 + srow) * 1024 + scg8;
    const bf16_t* Ag1 = A  + (size_t)(m0 + srow + 16) * 1024 + scg8;
    const bf16_t* Bg0 = Bt + (size_t)(n0 + srow) * 1024 + scg8;
    const bf16_t* Bg1 = Bt + (size_t)(n0 + srow + 16) * 1024 + scg8;

    const int rs = RD_SWZ8(quad, l15); // swizzled read slot

    f32x4 acc[4][4];
#pragma unroll
    for (int i = 0; i < 4; ++i)
#pragma unroll
        for (int j = 0; j < 4; ++j) acc[i][j] = (f32x4){0.f, 0.f, 0.f, 0.f};

    // prologue: tiles 0,1 into buffers 0,1
#pragma unroll
    for (int p = 0; p < 2; ++p) {
        const int k0 = p * 32;
        gl2lds16(Ag0 + k0, As + p * 4096 + (wid * 2 + 0) * 512);
        gl2lds16(Ag1 + k0, As + p * 4096 + (wid * 2 + 1) * 512);
        gl2lds16(Bg0 + k0, Bs + p * 4096 + (wid * 2 + 0) * 512);
        gl2lds16(Bg1 + k0, Bs + p * 4096 + (wid * 2 + 1) * 512);
    }

#pragma unroll
    for (int it = 0; it < 32; ++it) {
        if (it < 30) WAIT_VM4(); else WAIT_VM0();
        BARRIER();
        if (it < 30) {
            const int k0 = (it + 2) * 32;
            const int sb = (it + 2) % 3;          // compile-time after unroll
            gl2lds16(Ag0 + k0, As + sb * 4096 + (wid * 2 + 0) * 512);
            gl2lds16(Ag1 + k0, As + sb * 4096 + (wid * 2 + 1) * 512);
            gl2lds16(Bg0 + k0, Bs + sb * 4096 + (wid * 2 + 0) * 512);
            gl2lds16(Bg1 + k0, Bs + sb * 4096 + (wid * 2 + 1) * 512);
        }
        const int cb = it % 3;                    // compile-time after unroll
        bf16x8 af[4], bfr[4];
#pragma unroll
        for (int mt = 0; mt < 4; ++mt)
            af[mt] = *(const bf16x8*)&As[cb * 4096 + (wm + mt * 16 + l15) * 32 + rs];
#pragma unroll
        for (int nt = 0; nt < 4; ++nt)
            bfr[nt] = *(const bf16x8*)&Bs[cb * 4096 + (wn + nt * 16 + l15) * 32 + rs];
#pragma unroll
        for (int mt = 0; mt < 4; ++mt)
#pragma unroll
            for (int nt = 0; nt < 4; ++nt)
                acc[mt][nt] = MFMA_B16(bfr[nt], af[mt], acc[mt][nt]);  // lane=m, regs=n
    }

#pragma unroll
    for (int mt = 0; mt < 4; ++mt) {
        const int m = m0 + wm + mt * 16 + l15;
#pragma unroll
        for (int nt = 0; nt < 4; ++nt) {
            const int nb = n0 + wn + nt * 16 + quad * 4;
            if (MODE == 0) {
                *(f32x4*)&((float*)dst)[(size_t)m * 1024 + nb] = acc[mt][nt];
            } else if (MODE == 1) {
                const int bb = m >> 11, s = m & 2047;
                const int hh = nb >> 6, d = nb & 63;
                bf16x4 o;
#pragma unroll
                for (int u = 0; u < 4; ++u) o[u] = (bf16_t)acc[mt][nt][u];
                *(bf16x4*)&((bf16_t*)dst)[((size_t)(bb * 16 + hh) * 2048 + s) * 64 + d] = o;
            } else {
                // MODE 2: m = hd, n = s; store V^T[bh][d][s] contiguous in s
                const int bb = n0 >> 11;          // n-tile (128) within one bb
                const int hh = m >> 6, dd = m & 63;
                bf16x4 o;
#pragma unroll
                for (int u = 0; u < 4; ++u) o[u] = (bf16_t)acc[mt][nt][u];
                *(bf16x4*)&((bf16_t*)dst)[((size_t)(bb * 16 + hh) * 64 + dd) * 2048 + (nb & 2047)] = o;
            }
        }
    }

    if (MODE == 2 && vsum_out != nullptr) {
        const int bb = n0 >> 11;
#pragma unroll
        for (int mt = 0; mt < 4; ++mt) {
            float p = 0.f;
#pragma unroll
            for (int nt = 0; nt < 4; ++nt)
                p += acc[mt][nt][0] + acc[mt][nt][1] + acc[mt][nt][2] + acc[mt][nt][3];
            p += __shfl_xor(p, 16);   // reduce over quad (s sub-range)
            p += __shfl_xor(p, 32);
            if (quad == 0) {
                const int m = m0 + wm + mt * 16 + l15;   // hd
                atomicAdd(&vsum_out[(bb * 16 + (m >> 6)) * 64 + (m & 63)], p);
            }
        }
    }
}

// L2-aware remap: HW XCD = dispatch_linear % 8 = blockIdx.x. Each XCD owns a
// contiguous panel strip so A+B working set fits the 4 MB per-XCD L2.
__device__ __forceinline__ int remap_m(void) { return (blockIdx.x << 2) + (blockIdx.y >> 3); }
__device__ __forceinline__ int remap_n(void) { return blockIdx.y & 7; }

__global__ __launch_bounds__(256) void gemm_qkv_mfma(const bf16_t* __restrict__ xb,
                                                     const bf16_t* __restrict__ Wqt,
                                                     const bf16_t* __restrict__ Wkt,
                                                     const bf16_t* __restrict__ Wvt,
                                                     bf16_t* Qh, bf16_t* Kh, bf16_t* VhT,
                                                     float* vsp)
{
    __shared__ bf16_t As[12288];  // 3 x [128][32], slot-swizzled (shared by both paths)
    __shared__ bf16_t Bs[12288];
    if (blockIdx.z == 2) {
        // V^T GEMM: m-dim = hd (8 tiles), n-dim = s (32 tiles); swap remaps so
        // XCD x gets an s-strip (1MB xb) + full Wvt (2MB) -> L2-resident.
        mfma_gemm_body<2>(As, Bs, Wvt, xb, VhT, vsp, remap_n() * 128, remap_m() * 128);
    } else {
        const bf16_t* Bt = (blockIdx.z == 0) ? Wqt : Wkt;
        bf16_t* dst = (blockIdx.z == 0) ? Qh : Kh;
        mfma_gemm_body<1>(As, Bs, xb, Bt, dst, nullptr, remap_m() * 128, remap_n() * 128);
    }
}

__global__ __launch_bounds__(256) void gemm_out_mfma(const bf16_t* __restrict__ attn,
                                                     const bf16_t* __restrict__ Wot,
                                                     float* __restrict__ out)
{
    __shared__ bf16_t As[12288];
    __shared__ bf16_t Bs[12288];
    mfma_gemm_body<0>(As, Bs, attn, Wot, out, nullptr, remap_m() * 128, remap_n() * 128);
}

// ---------------------------------------------------------------------------
// Fused attention kernel, R11 = R7 EXACT (proven 48.0 us, VGPR 80) + two
// strictly-local micro-opts:
//  (1) phase-B QK->PV mid-barrier REMOVED: Ws rows [wid*32,wid*32+32) are
//      wave-private (written and read only by wave wid); VtL/Ks2 drained by
//      the post-staging __syncthreads; next overwrite fenced by loop-top
//      barrier. (Same argument correctness-verified in R9's variant.)
//  (2) s_setprio(1) around MFMA clusters (T5): 2 blocks/CU sit at different
//      phases -> scheduler favors the MFMA-issuing wave.
// R8/R9/R10 lesson encoded: do NOT restructure this kernel's block shape;
// allocator behavior is high-variance (64/128/252 VGPR outcomes).
// ---------------------------------------------------------------------------
__global__ __launch_bounds__(256) void attn_k(const bf16_t* __restrict__ Qh,
                                              const bf16_t* __restrict__ Kh,
                                              const bf16_t* __restrict__ VhT,
                                              const float* __restrict__ vsp,
                                              bf16_t* __restrict__ attn)
{
    __shared__ bf16_t Qs[8192];           // [2 half][128][32], lives A+B
    __shared__ float mr_sh[128];          // row max * SCALE, A -> B
    __shared__ __align__(16) char uni[35328];  // phase-exclusive union

    // phase A views
    bf16_t* KsB = (bf16_t*)uni;                       // 4 x [2][64][32] = 32768 B
    float*  msh = (float*)(uni + 32768);              // [4][8][16]      = 2048 B
    // phase B views
    bf16_t* Ks2 = (bf16_t*)uni;                       // [2][64][32]     = 8192 B
    bf16_t* VtL = (bf16_t*)(uni + 8192);              // [64 d][64 j] swz = 8192 B
    bf16_t* Ws  = (bf16_t*)(uni + 16384);             // [128][72]       = 18432 B
    float*  zsh = (float*)(uni + 34816);              // [4][32]         = 512 B

    const int tid = threadIdx.x;
    const int lane = tid & 63, wid = tid >> 6;
    const int l15 = lane & 15, quad = lane >> 4;

    const int f = blockIdx.x;
    const int seq = f >> 3;
    const int bh = (f & 7) + 8 * (seq >> 4);   // XCD-locality
    const int i0 = (seq & 15) * 128;
    const int b = bh >> 4, h = bh & 15;
    const bf16_t* Qb  = Qh  + (size_t)bh * 131072;
    const bf16_t* Kb  = Kh  + (size_t)bh * 131072;
    const bf16_t* VbT = VhT + (size_t)bh * 131072;

    const int ssw = SRC_SWZ8(lane);
    const int rs  = RD_SWZ8(quad, l15);

    // ======================= phase A: full-row max =========================
    // stage Q [2][128][32] (16 granules, 4/wave)
#pragma unroll
    for (int c = 0; c < 4; ++c) {
        const int gg = wid * 4 + c;
        const int half = gg >> 3;
        const int row = (gg & 7) * 16 + (lane >> 2);
        gl2lds16(Qb + (size_t)(i0 + row) * 64 + half * 32 + ssw, Qs + gg * 512);
    }
    // prologue: K chunks 0,1,2 into buffers 0,1,2 (2 gl2lds/thread/chunk)
#pragma unroll
    for (int p = 0; p < 3; ++p)
#pragma unroll
        for (int c = 0; c < 2; ++c) {
            const int gg = wid * 2 + c;               // 0..7
            const int half = gg >> 2;
            const int row = (gg & 3) * 16 + (lane >> 2);
            gl2lds16(Kb + (size_t)(p * 64 + row) * 64 + half * 32 + ssw,
                     KsB + p * 4096 + gg * 512);
        }
    __syncthreads();   // full drain: Q + chunks 0-2 resident

    bf16x8 af[8][2];
#pragma unroll
    for (int mt = 0; mt < 8; ++mt)
#pragma unroll
        for (int ks = 0; ks < 2; ++ks)
            af[mt][ks] = *(const bf16x8*)&Qs[ks * 4096 + (mt * 16 + l15) * 32 + rs];

    float vm[8];
#pragma unroll
    for (int mt = 0; mt < 8; ++mt) vm[mt] = -3.0e38f;

    for (int jc = 0; jc < 32; ++jc) {
        if (jc < 30) WAIT_VM4();        // own chunk-jc loads landed (3 chunks deep)
        else if (jc == 30) WAIT_VM2();
        else WAIT_VM0();
        BARRIER();                      // all waves: jc landed; jc-1 compute done
        if (jc < 29) {
            const int sb = (jc + 3) & 3;
#pragma unroll
            for (int c = 0; c < 2; ++c) {
                const int gg = wid * 2 + c;
                const int half = gg >> 2;
                const int row = (gg & 3) * 16 + (lane >> 2);
                gl2lds16(Kb + (size_t)((jc + 3) * 64 + row) * 64 + half * 32 + ssw,
                         KsB + sb * 4096 + gg * 512);
            }
        }
        const int cb = jc & 3;
        // wave's j-tile: jt = wid (PARTIAL over j; cross-wave combine via msh)
        const bf16x8 b0 = *(const bf16x8*)&KsB[cb * 4096 + (wid * 16 + l15) * 32 + rs];
        const bf16x8 b1 = *(const bf16x8*)&KsB[cb * 4096 + 2048 + (wid * 16 + l15) * 32 + rs];
        __builtin_amdgcn_s_setprio(1);
#pragma unroll
        for (int mt = 0; mt < 8; ++mt) {
            f32x4 t = (f32x4){0.f, 0.f, 0.f, 0.f};
            t = MFMA_B16(b0, af[mt][0], t);   // lane = i, regs = j
            t = MFMA_B16(b1, af[mt][1], t);
            const float u = fmaxf(fmaxf(t[0], t[1]), t[2]);      // v_max3
            vm[mt] = fmaxf(fmaxf(u, t[3]), vm[mt]);              // v_max3
        }
        __builtin_amdgcn_s_setprio(0);
    }

    // per-wave partial -> msh
#pragma unroll
    for (int mt = 0; mt < 8; ++mt) {
        float v = vm[mt];
        v = fmaxf(v, __shfl_xor(v, 16));
        v = fmaxf(v, __shfl_xor(v, 32));
        if (quad == 0) msh[(wid * 8 + mt) * 16 + l15] = v;
    }
    __syncthreads();

    // cross-wave combine -> mr_sh
    if (tid < 128) {
        const int mt = tid >> 4, il = tid & 15;
        const float v = fmaxf(fmaxf(msh[(0 * 8 + mt) * 16 + il], msh[(1 * 8 + mt) * 16 + il]),
                              fmaxf(msh[(2 * 8 + mt) * 16 + il], msh[(3 * 8 + mt) * 16 + il]));
        mr_sh[tid] = v * SCALE;
    }
    __syncthreads();   // mr_sh visible; ALL phase-A union reads complete

    // ======================= phase B: banded attention =====================
    bf16x8 aq[2][2];
#pragma unroll
    for (int t = 0; t < 2; ++t)
#pragma unroll
        for (int ks = 0; ks < 2; ++ks)
            aq[t][ks] = *(const bf16x8*)&Qs[ks * 4096 + ((wid * 2 + t) * 16 + l15) * 32 + rs];

    float mreg[2][4];
#pragma unroll
    for (int t = 0; t < 2; ++t)
#pragma unroll
        for (int r = 0; r < 4; ++r)
            mreg[t][r] = mr_sh[(wid * 2 + t) * 16 + quad * 4 + r];

    f32x4 vsd4[4];
#pragma unroll
    for (int dt = 0; dt < 4; ++dt)
        vsd4[dt] = *(const f32x4*)&vsp[bh * 64 + dt * 16 + quad * 4];

    f32x4 accO[2][4];
#pragma unroll
    for (int t = 0; t < 2; ++t)
#pragma unroll
        for (int dt = 0; dt < 4; ++dt) accO[t][dt] = (f32x4){0.f, 0.f, 0.f, 0.f};
    float zp[2][4] = {{0.f, 0.f, 0.f, 0.f}, {0.f, 0.f, 0.f, 0.f}};

    for (int cb2 = 0; cb2 < 6; ++cb2) {
        const int jb = i0 - 128 + cb2 * 64;
        if (jb < 0 || jb >= S_) continue;  // block-uniform

        __syncthreads();                   // prior chunk's Ks2/VtL readers done
        // K chunk (slot-swizzled, as before)
#pragma unroll
        for (int c = 0; c < 2; ++c) {
            const int gg = wid * 2 + c;
            const int half = gg >> 2;
            const int row = (gg & 3) * 16 + (lane >> 2);
            gl2lds16(Kb + (size_t)(jb + row) * 64 + half * 32 + ssw, Ks2 + gg * 512);
        }
        // V chunk from VhT: LDS [64 d][64 j], 128B rows = 8 slots; phys slot p
        // holds logical p^(d&7). Source pre-swizzled; dest wave-uniform.
#pragma unroll
        for (int c = 0; c < 2; ++c) {
            const int gg = wid * 2 + c;               // granule: 8 d-rows
            const int d = gg * 8 + (lane >> 3);
            const int jl = (lane & 7) ^ ((lane >> 3) & 7);
            gl2lds16(VbT + (size_t)d * 2048 + jb + jl * 8, VtL + gg * 512);
        }
        __syncthreads();

#pragma unroll
        for (int t = 0; t < 2; ++t) {
            const int mt = wid * 2 + t;
#pragma unroll
            for (int jt4 = 0; jt4 < 4; ++jt4) {
                const bf16x8 k0 = *(const bf16x8*)&Ks2[(jt4 * 16 + l15) * 32 + rs];
                const bf16x8 k1 = *(const bf16x8*)&Ks2[2048 + (jt4 * 16 + l15) * 32 + rs];
                f32x4 sc = (f32x4){0.f, 0.f, 0.f, 0.f};
                sc = MFMA_B16(aq[t][0], k0, sc);   // lane = j, regs = i
                sc = MFMA_B16(aq[t][1], k1, sc);
#pragma unroll
                for (int r = 0; r < 4; ++r) {
                    const int ig = i0 + mt * 16 + quad * 4 + r;
                    const int jg = jb + jt4 * 16 + l15;
                    const int dd = jg - ig;
                    const bool ok = (dd >= -128) && (dd <= 127);
                    const float e1 = __expf(sc[r] * SCALE - mreg[t][r]);
                    const float wv = ok ? (__expf(e1) - 1.0f) : 0.0f;
                    const bf16_t wb = (bf16_t)wv;
                    zp[t][r] += (float)wb;
                    Ws[(mt * 16 + quad * 4 + r) * 72 + jt4 * 16 + l15] = wb;
                }
            }
        }
        // NO barrier (R11): Ws rows [wid*32, wid*32+32) are wave-private
        // (written above by this wave, read below by this wave only); VtL was
        // drained by the post-staging __syncthreads; next overwrite of
        // Ks2/VtL is fenced by the loop-top __syncthreads.

        __builtin_amdgcn_s_setprio(1);
#pragma unroll
        for (int ks = 0; ks < 2; ++ks) {
            bf16x8 bv[4];
#pragma unroll
            for (int dt = 0; dt < 4; ++dt)
                bv[dt] = *(const bf16x8*)&VtL[(dt * 16 + l15) * 64 +
                                              (((ks * 4 + quad) ^ (l15 & 7)) * 8)];
#pragma unroll
            for (int t = 0; t < 2; ++t) {
                const int mt = wid * 2 + t;
                const bf16x8 aw = *(const bf16x8*)&Ws[(mt * 16 + l15) * 72 + ks * 32 + quad * 8];
#pragma unroll
                for (int dt = 0; dt < 4; ++dt)
                    accO[t][dt] = MFMA_B16(bv[dt], aw, accO[t][dt]);  // lane=i, regs=d
            }
        }
        __builtin_amdgcn_s_setprio(0);
    }

#pragma unroll
    for (int t = 0; t < 2; ++t)
#pragma unroll
        for (int r = 0; r < 4; ++r) {
            float z = zp[t][r];
            z += __shfl_xor(z, 1);
            z += __shfl_xor(z, 2);
            z += __shfl_xor(z, 4);
            z += __shfl_xor(z, 8);
            if (l15 == 0) zsh[wid * 32 + t * 16 + quad * 4 + r] = z + (float)S_;
        }
    __syncthreads();

#pragma unroll
    for (int t = 0; t < 2; ++t) {
        const float rz = 1.0f / zsh[wid * 32 + t * 16 + l15];
        const int irow = i0 + (wid * 2 + t) * 16 + l15;
#pragma unroll
        for (int dt = 0; dt < 4; ++dt) {
            bf16x4 o;
#pragma unroll
            for (int r = 0; r < 4; ++r)
                o[r] = (bf16_t)((accO[t][dt][r] + vsd4[dt][r]) * rz);
            *(bf16x4*)&attn[(size_t)(b * S_ + irow) * 1024 + h * 64 + dt * 16 + quad * 4] = o;
        }
    }
}

// ---------------------------------------------------------------------------
// Launch: 4 kernels
// ---------------------------------------------------------------------------
extern "C" void kernel_launch(void* const* d_in, const int* in_sizes, int n_in,
                              void* d_out, int out_size, void* d_ws, size_t ws_size,
                              hipStream_t stream)
{
    const float* x  = (const float*)d_in[0];
    const float* Wq = (const float*)d_in[1];
    const float* Wk = (const float*)d_in[2];
    const float* Wv = (const float*)d_in[3];
    const float* Wo = (const float*)d_in[4];
    float* out = (float*)d_out;

    char* ws = (char*)d_ws;
    bf16_t* xb   = (bf16_t*)(ws + 0);
    bf16_t* Wqt  = (bf16_t*)(ws + 8388608);
    bf16_t* Wkt  = (bf16_t*)(ws + 10485760);
    bf16_t* Wvt  = (bf16_t*)(ws + 12582912);
    bf16_t* Wot  = (bf16_t*)(ws + 14680064);
    bf16_t* Qh   = (bf16_t*)(ws + 16777216);   // [bh][s][64]
    bf16_t* Kh   = (bf16_t*)(ws + 25165824);   // [bh][s][64]
    bf16_t* VhT  = (bf16_t*)(ws + 33554432);   // [bh][d][s]  (V transposed)
    bf16_t* attn = (bf16_t*)(ws + 41943040);   // [m][1024]
    float*  vsp  = (float*)(ws + 50331648);    // [bh][64] f32, zeroed by prep

    prep<<<2049, 256, 0, stream>>>(x, Wq, Wk, Wv, Wo, xb, Wqt, Wkt, Wvt, Wot, vsp);
    gemm_qkv_mfma<<<dim3(8, 32, 3), 256, 0, stream>>>(xb, Wqt, Wkt, Wvt, Qh, Kh, VhT, vsp);
    attn_k<<<512, 256, 0, stream>>>(Qh, Kh, VhT, vsp, attn);
    gemm_out_mfma<<<dim3(8, 32), 256, 0, stream>>>(attn, Wot, out);
}

// Round 12
// 172.553 us; speedup vs baseline: 1.7311x; 1.0446x over previous
//
#include <hip/hip_runtime.h>
#include <math.h>

typedef __bf16 bf16_t;
typedef bf16_t bf16x8 __attribute__((ext_vector_type(8)));
typedef bf16_t bf16x4 __attribute__((ext_vector_type(4)));
typedef float f32x4 __attribute__((ext_vector_type(4)));

constexpr int S_ = 2048;
constexpr float SCALE = 0.125f;  // 1/sqrt(64)

#define MFMA_B16(a, b, c) __builtin_amdgcn_mfma_f32_16x16x32_bf16(a, b, c, 0, 0, 0)

// s_waitcnt immediates (gfx9 enc): [3:0]=vmcnt_lo, [6:4]=expcnt, [12:8]=lgkmcnt
#define WAIT_VM0() __builtin_amdgcn_s_waitcnt(0x0F70)
#define WAIT_VM2() __builtin_amdgcn_s_waitcnt(0x0F72)
#define WAIT_VM4() __builtin_amdgcn_s_waitcnt(0x0F74)
#define BARRIER()  __builtin_amdgcn_s_barrier()

typedef __attribute__((address_space(1))) const void* as1_cvp;
typedef __attribute__((address_space(3))) void* as3_vp;

__device__ __forceinline__ void gl2lds16(const void* g, void* l)
{
    __builtin_amdgcn_global_load_lds((as1_cvp)g, (as3_vp)l, 16, 0, 0);
}

// ---------------------------------------------------------------------------
// LDS slot swizzle for row-major [*][32]bf16 tiles (64B rows, 4x16B slots):
//   slot' = slot ^ ((row>>1)&3)
// Linear LDS dest (global_load_lds requirement) + pre-swizzled global source
// column; fragment reads apply the same XOR. 2-way (free) bank aliasing.
// ---------------------------------------------------------------------------
#define SRC_SWZ8(lane) ((((lane) & 3) ^ (((lane) >> 3) & 3)) * 8)
#define RD_SWZ8(quad, l15) ((((quad) ^ (((l15) >> 1) & 3))) * 8)

// ---------------------------------------------------------------------------
// prep: cast x -> bf16 (blocks 0..1023), transpose-cast 4 weights (1024..2047),
// zero vsp (block 2048)
// ---------------------------------------------------------------------------
__global__ __launch_bounds__(256) void prep(const float* __restrict__ x,
                                            const float* __restrict__ Wq,
                                            const float* __restrict__ Wk,
                                            const float* __restrict__ Wv,
                                            const float* __restrict__ Wo,
                                            bf16_t* __restrict__ xb,
                                            bf16_t* __restrict__ Wqt,
                                            bf16_t* __restrict__ Wkt,
                                            bf16_t* __restrict__ Wvt,
                                            bf16_t* __restrict__ Wot,
                                            float* __restrict__ vsp)
{
    __shared__ float T[64][65];
    const int blk = blockIdx.x;
    const int tid = threadIdx.x;
    if (blk < 1024) {
#pragma unroll
        for (int u = 0; u < 4; ++u) {
            const int g = blk * 1024 + u * 256 + tid;
            const float4 v = ((const float4*)x)[g];
            bf16x4 o;
            o[0] = (bf16_t)v.x; o[1] = (bf16_t)v.y;
            o[2] = (bf16_t)v.z; o[3] = (bf16_t)v.w;
            *(bf16x4*)&xb[(size_t)g * 4] = o;
        }
    } else if (blk < 2048) {
        const int rem = blk - 1024;
        const int wsel = rem >> 8, t = rem & 255;
        const float* src = (wsel == 0) ? Wq : (wsel == 1) ? Wk : (wsel == 2) ? Wv : Wo;
        bf16_t* dst = (wsel == 0) ? Wqt : (wsel == 1) ? Wkt : (wsel == 2) ? Wvt : Wot;
        const int k0 = (t >> 4) * 64, n0 = (t & 15) * 64;
        const int rr = tid >> 4, c4 = (tid & 15) * 4;
#pragma unroll
        for (int u = 0; u < 4; ++u) {
            const float4 v = *(const float4*)&src[(size_t)(k0 + u * 16 + rr) * 1024 + n0 + c4];
            T[u * 16 + rr][c4 + 0] = v.x; T[u * 16 + rr][c4 + 1] = v.y;
            T[u * 16 + rr][c4 + 2] = v.z; T[u * 16 + rr][c4 + 3] = v.w;
        }
        __syncthreads();
#pragma unroll
        for (int u = 0; u < 4; ++u) {
            bf16x4 o;
#pragma unroll
            for (int e = 0; e < 4; ++e) o[e] = (bf16_t)T[c4 + e][u * 16 + rr];
            *(bf16x4*)&dst[(size_t)(n0 + u * 16 + rr) * 1024 + k0 + c4] = o;
        }
    } else {
#pragma unroll
        for (int u = 0; u < 8; ++u) vsp[u * 256 + tid] = 0.f;
    }
}

// ---------------------------------------------------------------------------
// bf16 MFMA GEMM, tri-buffered, fully unrolled K-loop (static buffer indices).
// 2 tiles in flight, vmcnt(4) retires only the older. LDS slot-swizzled.
// MODE 0: f32 store to dst[m][1024].
// MODE 1: bf16 store to [bh][s][64] (Q/K heads layout).
// MODE 2: bf16 store TRANSPOSED to VhT[bh][d][s] (A=Wvt, Bt=xb: m=hd, n=s)
//         + vsum (sum over s of V) from f32 acc.
// ---------------------------------------------------------------------------
template <int MODE>
__device__ __forceinline__ void mfma_gemm_body(bf16_t* __restrict__ As,
                                               bf16_t* __restrict__ Bs,
                                               const bf16_t* __restrict__ A,
                                               const bf16_t* __restrict__ Bt,
                                               void* __restrict__ dst,
                                               float* __restrict__ vsum_out,
                                               int m0, int n0)
{
    const int tid = threadIdx.x;
    const int lane = tid & 63, wid = tid >> 6;
    const int l15 = lane & 15, quad = lane >> 4;
    const int wm = (wid & 1) * 64, wn = (wid >> 1) * 64;

    const int srow = wid * 32 + (lane >> 2);
    const int scg8 = SRC_SWZ8(lane);   // pre-swizzled source slot
    const bf16_t* Ag0 = A  + (size_t)(m0 + srow) * 1024 + scg8;
    const bf16_t* Ag1 = A  + (size_t)(m0 + srow + 16) * 1024 + scg8;
    const bf16_t* Bg0 = Bt + (size_t)(n0 + srow) * 1024 + scg8;
    const bf16_t* Bg1 = Bt + (size_t)(n0 + srow + 16) * 1024 + scg8;

    const int rs = RD_SWZ8(quad, l15); // swizzled read slot

    f32x4 acc[4][4];
#pragma unroll
    for (int i = 0; i < 4; ++i)
#pragma unroll
        for (int j = 0; j < 4; ++j) acc[i][j] = (f32x4){0.f, 0.f, 0.f, 0.f};

    // prologue: tiles 0,1 into buffers 0,1
#pragma unroll
    for (int p = 0; p < 2; ++p) {
        const int k0 = p * 32;
        gl2lds16(Ag0 + k0, As + p * 4096 + (wid * 2 + 0) * 512);
        gl2lds16(Ag1 + k0, As + p * 4096 + (wid * 2 + 1) * 512);
        gl2lds16(Bg0 + k0, Bs + p * 4096 + (wid * 2 + 0) * 512);
        gl2lds16(Bg1 + k0, Bs + p * 4096 + (wid * 2 + 1) * 512);
    }

#pragma unroll
    for (int it = 0; it < 32; ++it) {
        if (it < 30) WAIT_VM4(); else WAIT_VM0();
        BARRIER();
        if (it < 30) {
            const int k0 = (it + 2) * 32;
            const int sb = (it + 2) % 3;          // compile-time after unroll
            gl2lds16(Ag0 + k0, As + sb * 4096 + (wid * 2 + 0) * 512);
            gl2lds16(Ag1 + k0, As + sb * 4096 + (wid * 2 + 1) * 512);
            gl2lds16(Bg0 + k0, Bs + sb * 4096 + (wid * 2 + 0) * 512);
            gl2lds16(Bg1 + k0, Bs + sb * 4096 + (wid * 2 + 1) * 512);
        }
        const int cb = it % 3;                    // compile-time after unroll
        bf16x8 af[4], bfr[4];
#pragma unroll
        for (int mt = 0; mt < 4; ++mt)
            af[mt] = *(const bf16x8*)&As[cb * 4096 + (wm + mt * 16 + l15) * 32 + rs];
#pragma unroll
        for (int nt = 0; nt < 4; ++nt)
            bfr[nt] = *(const bf16x8*)&Bs[cb * 4096 + (wn + nt * 16 + l15) * 32 + rs];
#pragma unroll
        for (int mt = 0; mt < 4; ++mt)
#pragma unroll
            for (int nt = 0; nt < 4; ++nt)
                acc[mt][nt] = MFMA_B16(bfr[nt], af[mt], acc[mt][nt]);  // lane=m, regs=n
    }

#pragma unroll
    for (int mt = 0; mt < 4; ++mt) {
        const int m = m0 + wm + mt * 16 + l15;
#pragma unroll
        for (int nt = 0; nt < 4; ++nt) {
            const int nb = n0 + wn + nt * 16 + quad * 4;
            if (MODE == 0) {
                *(f32x4*)&((float*)dst)[(size_t)m * 1024 + nb] = acc[mt][nt];
            } else if (MODE == 1) {
                const int bb = m >> 11, s = m & 2047;
                const int hh = nb >> 6, d = nb & 63;
                bf16x4 o;
#pragma unroll
                for (int u = 0; u < 4; ++u) o[u] = (bf16_t)acc[mt][nt][u];
                *(bf16x4*)&((bf16_t*)dst)[((size_t)(bb * 16 + hh) * 2048 + s) * 64 + d] = o;
            } else {
                // MODE 2: m = hd, n = s; store V^T[bh][d][s] contiguous in s
                const int bb = n0 >> 11;          // n-tile (128) within one bb
                const int hh = m >> 6, dd = m & 63;
                bf16x4 o;
#pragma unroll
                for (int u = 0; u < 4; ++u) o[u] = (bf16_t)acc[mt][nt][u];
                *(bf16x4*)&((bf16_t*)dst)[((size_t)(bb * 16 + hh) * 64 + dd) * 2048 + (nb & 2047)] = o;
            }
        }
    }

    if (MODE == 2 && vsum_out != nullptr) {
        const int bb = n0 >> 11;
#pragma unroll
        for (int mt = 0; mt < 4; ++mt) {
            float p = 0.f;
#pragma unroll
            for (int nt = 0; nt < 4; ++nt)
                p += acc[mt][nt][0] + acc[mt][nt][1] + acc[mt][nt][2] + acc[mt][nt][3];
            p += __shfl_xor(p, 16);   // reduce over quad (s sub-range)
            p += __shfl_xor(p, 32);
            if (quad == 0) {
                const int m = m0 + wm + mt * 16 + l15;   // hd
                atomicAdd(&vsum_out[(bb * 16 + (m >> 6)) * 64 + (m & 63)], p);
            }
        }
    }
}

// L2-aware remap: HW XCD = dispatch_linear % 8 = blockIdx.x. Each XCD owns a
// contiguous panel strip so A+B working set fits the 4 MB per-XCD L2.
__device__ __forceinline__ int remap_m(void) { return (blockIdx.x << 2) + (blockIdx.y >> 3); }
__device__ __forceinline__ int remap_n(void) { return blockIdx.y & 7; }

__global__ __launch_bounds__(256) void gemm_qkv_mfma(const bf16_t* __restrict__ xb,
                                                     const bf16_t* __restrict__ Wqt,
                                                     const bf16_t* __restrict__ Wkt,
                                                     const bf16_t* __restrict__ Wvt,
                                                     bf16_t* Qh, bf16_t* Kh, bf16_t* VhT,
                                                     float* vsp)
{
    __shared__ bf16_t As[12288];  // 3 x [128][32], slot-swizzled (shared by both paths)
    __shared__ bf16_t Bs[12288];
    if (blockIdx.z == 2) {
        // V^T GEMM: m-dim = hd (8 tiles), n-dim = s (32 tiles); swap remaps so
        // XCD x gets an s-strip (1MB xb) + full Wvt (2MB) -> L2-resident.
        mfma_gemm_body<2>(As, Bs, Wvt, xb, VhT, vsp, remap_n() * 128, remap_m() * 128);
    } else {
        const bf16_t* Bt = (blockIdx.z == 0) ? Wqt : Wkt;
        bf16_t* dst = (blockIdx.z == 0) ? Qh : Kh;
        mfma_gemm_body<1>(As, Bs, xb, Bt, dst, nullptr, remap_m() * 128, remap_n() * 128);
    }
}

__global__ __launch_bounds__(256) void gemm_out_mfma(const bf16_t* __restrict__ attn,
                                                     const bf16_t* __restrict__ Wot,
                                                     float* __restrict__ out)
{
    __shared__ bf16_t As[12288];
    __shared__ bf16_t Bs[12288];
    mfma_gemm_body<0>(As, Bs, attn, Wot, out, nullptr, remap_m() * 128, remap_n() * 128);
}

// ---------------------------------------------------------------------------
// Fused attention kernel, R12: phase A goes BARRIER-FREE.
// Key insight: phase A's K slices are WAVE-PRIVATE (wave wid reads only rows
// wid*16+l15, 16B/lane) — the LDS staging + 64 barriers existed only as an
// artifact of gl2lds. Now each wave streams K fragments global->register
// (per-lane dwordx4, 16B aligned, L2-resident) with a 1-chunk register
// double-buffer; compiler auto-waitcnt pipelines load(jc+1) under MFMA(jc).
// Waves run fully desynchronized -> setprio is in its documented +4-7%
// regime (independent waves) and stays around the phase-A MFMA cluster.
// Phase B: R7-EXACT (mid-barrier present, no setprio) to isolate the change.
// Per-output arithmetic and op order identical to R7 -> absmax unchanged.
// LDS: Qs 16384 + mr_sh 512 + union(A: msh 2048 | B: 35328) = 52224.
// ---------------------------------------------------------------------------
__global__ __launch_bounds__(256) void attn_k(const bf16_t* __restrict__ Qh,
                                              const bf16_t* __restrict__ Kh,
                                              const bf16_t* __restrict__ VhT,
                                              const float* __restrict__ vsp,
                                              bf16_t* __restrict__ attn)
{
    __shared__ bf16_t Qs[8192];           // [2 half][128][32], lives A+B
    __shared__ float mr_sh[128];          // row max * SCALE, A -> B
    __shared__ __align__(16) char uni[35328];  // phase-exclusive union

    // phase A views
    float*  msh = (float*)uni;                        // [4][8][16]      = 2048 B
    // phase B views
    bf16_t* Ks2 = (bf16_t*)uni;                       // [2][64][32]     = 8192 B
    bf16_t* VtL = (bf16_t*)(uni + 8192);              // [64 d][64 j] swz = 8192 B
    bf16_t* Ws  = (bf16_t*)(uni + 16384);             // [128][72]       = 18432 B
    float*  zsh = (float*)(uni + 34816);              // [4][32]         = 512 B

    const int tid = threadIdx.x;
    const int lane = tid & 63, wid = tid >> 6;
    const int l15 = lane & 15, quad = lane >> 4;

    const int f = blockIdx.x;
    const int seq = f >> 3;
    const int bh = (f & 7) + 8 * (seq >> 4);   // XCD-locality
    const int i0 = (seq & 15) * 128;
    const int b = bh >> 4, h = bh & 15;
    const bf16_t* Qb  = Qh  + (size_t)bh * 131072;
    const bf16_t* Kb  = Kh  + (size_t)bh * 131072;
    const bf16_t* VbT = VhT + (size_t)bh * 131072;

    const int ssw = SRC_SWZ8(lane);
    const int rs  = RD_SWZ8(quad, l15);

    // ======================= phase A: full-row max =========================
    // stage Q [2][128][32] (16 granules, 4/wave) — LDS (shared by B)
#pragma unroll
    for (int c = 0; c < 4; ++c) {
        const int gg = wid * 4 + c;
        const int half = gg >> 3;
        const int row = (gg & 7) * 16 + (lane >> 2);
        gl2lds16(Qb + (size_t)(i0 + row) * 64 + half * 32 + ssw, Qs + gg * 512);
    }
    __syncthreads();   // Q resident

    bf16x8 af[8][2];
#pragma unroll
    for (int mt = 0; mt < 8; ++mt)
#pragma unroll
        for (int ks = 0; ks < 2; ++ks)
            af[mt][ks] = *(const bf16x8*)&Qs[ks * 4096 + (mt * 16 + l15) * 32 + rs];

    float vm[8];
#pragma unroll
    for (int mt = 0; mt < 8; ++mt) vm[mt] = -3.0e38f;

    // wave-private K fragment stream: rows wid*16+l15, depth quad*8 (+32).
    // chunk jc covers j = jc*64..+64; this wave's j-tile = wid*16 within it.
    const bf16_t* kf0 = Kb + (size_t)(wid * 16 + l15) * 64 + quad * 8;
    bf16x8 k0 = *(const bf16x8*)(kf0);
    bf16x8 k1 = *(const bf16x8*)(kf0 + 32);

    for (int jc = 0; jc < 32; ++jc) {
        // issue next chunk's loads (clamped at the tail; re-read is harmless)
        const bf16_t* pn = kf0 + (size_t)((jc < 31) ? (jc + 1) : 31) * 4096;
        const bf16x8 n0 = *(const bf16x8*)(pn);
        const bf16x8 n1 = *(const bf16x8*)(pn + 32);
        __builtin_amdgcn_s_setprio(1);
#pragma unroll
        for (int mt = 0; mt < 8; ++mt) {
            f32x4 t = (f32x4){0.f, 0.f, 0.f, 0.f};
            t = MFMA_B16(k0, af[mt][0], t);   // lane = i, regs = j
            t = MFMA_B16(k1, af[mt][1], t);
            const float u = fmaxf(fmaxf(t[0], t[1]), t[2]);      // v_max3
            vm[mt] = fmaxf(fmaxf(u, t[3]), vm[mt]);              // v_max3
        }
        __builtin_amdgcn_s_setprio(0);
        k0 = n0; k1 = n1;
    }

    // per-wave partial -> msh
#pragma unroll
    for (int mt = 0; mt < 8; ++mt) {
        float v = vm[mt];
        v = fmaxf(v, __shfl_xor(v, 16));
        v = fmaxf(v, __shfl_xor(v, 32));
        if (quad == 0) msh[(wid * 8 + mt) * 16 + l15] = v;
    }
    __syncthreads();

    // cross-wave combine -> mr_sh
    if (tid < 128) {
        const int mt = tid >> 4, il = tid & 15;
        const float v = fmaxf(fmaxf(msh[(0 * 8 + mt) * 16 + il], msh[(1 * 8 + mt) * 16 + il]),
                              fmaxf(msh[(2 * 8 + mt) * 16 + il], msh[(3 * 8 + mt) * 16 + il]));
        mr_sh[tid] = v * SCALE;
    }
    __syncthreads();   // mr_sh visible; ALL phase-A union reads complete

    // ======================= phase B: banded attention (R7-exact) ==========
    bf16x8 aq[2][2];
#pragma unroll
    for (int t = 0; t < 2; ++t)
#pragma unroll
        for (int ks = 0; ks < 2; ++ks)
            aq[t][ks] = *(const bf16x8*)&Qs[ks * 4096 + ((wid * 2 + t) * 16 + l15) * 32 + rs];

    float mreg[2][4];
#pragma unroll
    for (int t = 0; t < 2; ++t)
#pragma unroll
        for (int r = 0; r < 4; ++r)
            mreg[t][r] = mr_sh[(wid * 2 + t) * 16 + quad * 4 + r];

    f32x4 vsd4[4];
#pragma unroll
    for (int dt = 0; dt < 4; ++dt)
        vsd4[dt] = *(const f32x4*)&vsp[bh * 64 + dt * 16 + quad * 4];

    f32x4 accO[2][4];
#pragma unroll
    for (int t = 0; t < 2; ++t)
#pragma unroll
        for (int dt = 0; dt < 4; ++dt) accO[t][dt] = (f32x4){0.f, 0.f, 0.f, 0.f};
    float zp[2][4] = {{0.f, 0.f, 0.f, 0.f}, {0.f, 0.f, 0.f, 0.f}};

    for (int cb2 = 0; cb2 < 6; ++cb2) {
        const int jb = i0 - 128 + cb2 * 64;
        if (jb < 0 || jb >= S_) continue;  // block-uniform

        __syncthreads();                   // prior chunk's Ks2/VtL readers done
        // K chunk (slot-swizzled)
#pragma unroll
        for (int c = 0; c < 2; ++c) {
            const int gg = wid * 2 + c;
            const int half = gg >> 2;
            const int row = (gg & 3) * 16 + (lane >> 2);
            gl2lds16(Kb + (size_t)(jb + row) * 64 + half * 32 + ssw, Ks2 + gg * 512);
        }
        // V chunk from VhT: LDS [64 d][64 j], 128B rows = 8 slots; phys slot p
        // holds logical p^(d&7). Source pre-swizzled; dest wave-uniform.
#pragma unroll
        for (int c = 0; c < 2; ++c) {
            const int gg = wid * 2 + c;               // granule: 8 d-rows
            const int d = gg * 8 + (lane >> 3);
            const int jl = (lane & 7) ^ ((lane >> 3) & 7);
            gl2lds16(VbT + (size_t)d * 2048 + jb + jl * 8, VtL + gg * 512);
        }
        __syncthreads();

#pragma unroll
        for (int t = 0; t < 2; ++t) {
            const int mt = wid * 2 + t;
#pragma unroll
            for (int jt4 = 0; jt4 < 4; ++jt4) {
                const bf16x8 kk0 = *(const bf16x8*)&Ks2[(jt4 * 16 + l15) * 32 + rs];
                const bf16x8 kk1 = *(const bf16x8*)&Ks2[2048 + (jt4 * 16 + l15) * 32 + rs];
                f32x4 sc = (f32x4){0.f, 0.f, 0.f, 0.f};
                sc = MFMA_B16(aq[t][0], kk0, sc);   // lane = j, regs = i
                sc = MFMA_B16(aq[t][1], kk1, sc);
#pragma unroll
                for (int r = 0; r < 4; ++r) {
                    const int ig = i0 + mt * 16 + quad * 4 + r;
                    const int jg = jb + jt4 * 16 + l15;
                    const int dd = jg - ig;
                    const bool ok = (dd >= -128) && (dd <= 127);
                    const float e1 = __expf(sc[r] * SCALE - mreg[t][r]);
                    const float wv = ok ? (__expf(e1) - 1.0f) : 0.0f;
                    const bf16_t wb = (bf16_t)wv;
                    zp[t][r] += (float)wb;
                    Ws[(mt * 16 + quad * 4 + r) * 72 + jt4 * 16 + l15] = wb;
                }
            }
        }
        __syncthreads();

#pragma unroll
        for (int ks = 0; ks < 2; ++ks) {
            bf16x8 bv[4];
#pragma unroll
            for (int dt = 0; dt < 4; ++dt)
                bv[dt] = *(const bf16x8*)&VtL[(dt * 16 + l15) * 64 +
                                              (((ks * 4 + quad) ^ (l15 & 7)) * 8)];
#pragma unroll
            for (int t = 0; t < 2; ++t) {
                const int mt = wid * 2 + t;
                const bf16x8 aw = *(const bf16x8*)&Ws[(mt * 16 + l15) * 72 + ks * 32 + quad * 8];
#pragma unroll
                for (int dt = 0; dt < 4; ++dt)
                    accO[t][dt] = MFMA_B16(bv[dt], aw, accO[t][dt]);  // lane=i, regs=d
            }
        }
    }

#pragma unroll
    for (int t = 0; t < 2; ++t)
#pragma unroll
        for (int r = 0; r < 4; ++r) {
            float z = zp[t][r];
            z += __shfl_xor(z, 1);
            z += __shfl_xor(z, 2);
            z += __shfl_xor(z, 4);
            z += __shfl_xor(z, 8);
            if (l15 == 0) zsh[wid * 32 + t * 16 + quad * 4 + r] = z + (float)S_;
        }
    __syncthreads();

#pragma unroll
    for (int t = 0; t < 2; ++t) {
        const float rz = 1.0f / zsh[wid * 32 + t * 16 + l15];
        const int irow = i0 + (wid * 2 + t) * 16 + l15;
#pragma unroll
        for (int dt = 0; dt < 4; ++dt) {
            bf16x4 o;
#pragma unroll
            for (int r = 0; r < 4; ++r)
                o[r] = (bf16_t)((accO[t][dt][r] + vsd4[dt][r]) * rz);
            *(bf16x4*)&attn[(size_t)(b * S_ + irow) * 1024 + h * 64 + dt * 16 + quad * 4] = o;
        }
    }
}

// ---------------------------------------------------------------------------
// Launch: 4 kernels
// ---------------------------------------------------------------------------
extern "C" void kernel_launch(void* const* d_in, const int* in_sizes, int n_in,
                              void* d_out, int out_size, void* d_ws, size_t ws_size,
                              hipStream_t stream)
{
    const float* x  = (const float*)d_in[0];
    const float* Wq = (const float*)d_in[1];
    const float* Wk = (const float*)d_in[2];
    const float* Wv = (const float*)d_in[3];
    const float* Wo = (const float*)d_in[4];
    float* out = (float*)d_out;

    char* ws = (char*)d_ws;
    bf16_t* xb   = (bf16_t*)(ws + 0);
    bf16_t* Wqt  = (bf16_t*)(ws + 8388608);
    bf16_t* Wkt  = (bf16_t*)(ws + 10485760);
    bf16_t* Wvt  = (bf16_t*)(ws + 12582912);
    bf16_t* Wot  = (bf16_t*)(ws + 14680064);
    bf16_t* Qh   = (bf16_t*)(ws + 16777216);   // [bh][s][64]
    bf16_t* Kh   = (bf16_t*)(ws + 25165824);   // [bh][s][64]
    bf16_t* VhT  = (bf16_t*)(ws + 33554432);   // [bh][d][s]  (V transposed)
    bf16_t* attn = (bf16_t*)(ws + 41943040);   // [m][1024]
    float*  vsp  = (float*)(ws + 50331648);    // [bh][64] f32, zeroed by prep

    prep<<<2049, 256, 0, stream>>>(x, Wq, Wk, Wv, Wo, xb, Wqt, Wkt, Wvt, Wot, vsp);
    gemm_qkv_mfma<<<dim3(8, 32, 3), 256, 0, stream>>>(xb, Wqt, Wkt, Wvt, Qh, Kh, VhT, vsp);
    attn_k<<<512, 256, 0, stream>>>(Qh, Kh, VhT, vsp, attn);
    gemm_out_mfma<<<dim3(8, 32), 256, 0, stream>>>(attn, Wot, out);
}